// Round 11
// baseline (1194.172 us; speedup 1.0000x reference)
//
#include <hip/hip_runtime.h>
#include <hip/hip_bf16.h>

// ============================================================================
// TransformerChoiceNet forward. Round 11: attention LDS-free inner loop —
// zero-padded 16x16x32 PV MFMAs consume the S^T C-layout directly (keys
// quad*4+r at A-frag positions quad*8+{0..3}, zeros above, V supplies
// matching 8B), eliminating the Pbuf LDS round-trip, its bank conflicts and
// its 20KB occupancy cap (2KB Smask only -> ~8 blocks/CU). No pipelining
// (r9/r10 proven neutral). Fast gelu tanh (libm tanhf ~20 insts -> 6).
// B=128 S=512 D=64 H=256 NH=8 HD=32, M=B*S=65536.
// ============================================================================

#define Bb  128
#define Ss  512
#define Hh  256
#define NHh 8
#define Mm  (Bb*Ss)

typedef unsigned short bf16_t;
typedef __attribute__((ext_vector_type(8))) short short8;
typedef __attribute__((ext_vector_type(4))) float f32x4;

__device__ __forceinline__ float bf2f(bf16_t h){
  union { unsigned int u; float f; } v; v.u = ((unsigned int)h)<<16; return v.f;
}
__device__ __forceinline__ bf16_t f2bf(float f){
  union { float f; unsigned int u; } v; v.f = f;
  unsigned int r = (v.u + 0x7fffu + ((v.u>>16)&1u)) >> 16;   // RNE
  return (bf16_t)r;
}
__device__ __forceinline__ unsigned pk_bf16(float a, float b){  // packed RNE cvt
  union { __hip_bfloat162 h; unsigned u; } v;
  v.h = __float22bfloat162_rn(float2{a,b});
  return v.u;
}
__device__ __forceinline__ short8 ld_bf8(const bf16_t* p){   // 16B load
  union { uint4 u; short8 s; } v; v.u = *(const uint4*)p; return v.s;
}
__device__ __forceinline__ void gload16(const bf16_t* g, bf16_t* l){
  __builtin_amdgcn_global_load_lds(
      (const __attribute__((address_space(1))) void*)g,
      (__attribute__((address_space(3))) void*)l, 16, 0, 0);
}
__device__ __forceinline__ float gelu_f(float x){
  // NewGELU; tanh via native exp + rcp: tanh(u) = 1 - 2/(e^{2u}+1)
  float u = 0.7978845608028654f*(x + 0.044715f*x*x*x);
  float e = __expf(2.0f*u);                       // inf/0 at extremes -> th=+/-1
  float th = 1.0f - 2.0f*__builtin_amdgcn_rcpf(e + 1.0f);
  return 0.5f*x*(1.0f + th);
}

// ---------------- weight prep: fp32 W[k][n] -> bf16 Wt[n][k] ------------------
struct PrepDesc { const float* s; unsigned off; int K; };
struct Prep18  { PrepDesc d[18]; };

__global__ __launch_bounds__(256) void k_prep(Prep18 p, bf16_t* __restrict__ arena)
{
  PrepDesc dd = p.d[blockIdx.y];
  int i = blockIdx.x*256 + threadIdx.x;
  if (i < dd.K*256){
    int k = i>>8, n = i&255;
    arena[dd.off + n*dd.K + k] = f2bf(dd.s[i]);
  }
}

// ---------------- LN0 (two gains) + valid mask; bf16 out ----------------------
__global__ __launch_bounds__(256) void k_ln0(const float* __restrict__ src,
    const float* __restrict__ gs, const float* __restrict__ bs,
    const float* __restrict__ gt, const float* __restrict__ bt,
    bf16_t* __restrict__ xs, bf16_t* __restrict__ xt, float* __restrict__ valid)
{
  int row  = blockIdx.x*4 + (threadIdx.x>>6);
  int lane = threadIdx.x & 63;
  float x = src[(size_t)row*64 + lane];
  float s = x;
  #pragma unroll
  for (int o=32;o>0;o>>=1) s += __shfl_xor(s,o);
  float mean = s*(1.0f/64.0f);
  float d = x - mean;
  float ss = d*d;
  #pragma unroll
  for (int o=32;o>0;o>>=1) ss += __shfl_xor(ss,o);
  float r = rsqrtf(ss*(1.0f/64.0f) + 1e-5f);
  float xn = d*r;
  xs[(size_t)row*64+lane] = f2bf(xn*gs[lane] + bs[lane]);
  xt[(size_t)row*64+lane] = f2bf(xn*gt[lane] + bt[lane]);
  if (lane==0) valid[row] = (s != 0.0f) ? 1.0f : 0.0f;
}

// ---------------- merged independent GEMMs (QKV trio / emb pair) --------------
struct GemmJob  { const bf16_t* A; const bf16_t* Wt; const float* bias; bf16_t* C; int outm; };
struct GemmJobs { GemmJob j[3]; };

__global__ __launch_bounds__(256,4) void k_gemm3(GemmJobs jobs, int K)
{
  __shared__ bf16_t As[8*512];    // 8 KB
  __shared__ bf16_t Bs[32*512];   // 32 KB
  GemmJob jb = jobs.j[blockIdx.y];
  int t = threadIdx.x, w = t>>6, lane = t&63, l15 = lane&15, quad = lane>>4;
  int m0 = blockIdx.x*64;
  f32x4 z = {0.f,0.f,0.f,0.f};
  f32x4 acc[4][4] = {{z,z,z,z},{z,z,z,z},{z,z,z,z},{z,z,z,z}};

  for (int k0=0; k0<K; k0+=64){
    #pragma unroll
    for (int j=0; j<2; j++){
      int id = 2*w + j; int kc32 = id>>2, mt = id&3;
      gload16(jb.A + (size_t)(m0 + mt*16 + l15)*K + k0 + kc32*32 + quad*8,
              &As[id*512]);
    }
    #pragma unroll
    for (int j=0; j<8; j++){
      int id = 8*w + j; int kc32 = id>>4, gnt = id&15;
      gload16(jb.Wt + (size_t)(gnt*16 + l15)*K + k0 + kc32*32 + quad*8,
              &Bs[id*512]);
    }
    __syncthreads();
    #pragma unroll
    for (int kc=0; kc<2; kc++){
      short8 a[4], b[4];
      #pragma unroll
      for (int mt=0; mt<4; mt++) a[mt] = ld_bf8(&As[(kc*4+mt)*512 + lane*8]);
      #pragma unroll
      for (int nt=0; nt<4; nt++) b[nt] = ld_bf8(&Bs[(kc*16 + w*4 + nt)*512 + lane*8]);
      #pragma unroll
      for (int mt=0; mt<4; mt++)
        #pragma unroll
        for (int nt=0; nt<4; nt++)
          acc[mt][nt] = __builtin_amdgcn_mfma_f32_16x16x32_bf16(a[mt], b[nt], acc[mt][nt], 0,0,0);
    }
    __syncthreads();
  }

  float bv[4];
  #pragma unroll
  for (int nt=0; nt<4; nt++) bv[nt] = jb.bias[w*64 + nt*16 + l15];

  if (jb.outm == 0){
    #pragma unroll
    for (int mt=0; mt<4; mt++)
      #pragma unroll
      for (int nt=0; nt<4; nt++){
        int m = m0 + mt*16 + quad*4;
        int col = w*64 + nt*16 + l15;
        #pragma unroll
        for (int r=0; r<4; r++)
          jb.C[(size_t)(m+r)*256 + col] = f2bf(acc[mt][nt][r] + bv[nt]);
      }
  } else {
    // VT[b][n][s]: 4 consecutive r = 4 consecutive s -> one 8B packed store
    #pragma unroll
    for (int mt=0; mt<4; mt++)
      #pragma unroll
      for (int nt=0; nt<4; nt++){
        int m = m0 + mt*16 + quad*4;
        int col = w*64 + nt*16 + l15;
        uint2 pk = { pk_bf16(acc[mt][nt][0]+bv[nt], acc[mt][nt][1]+bv[nt]),
                     pk_bf16(acc[mt][nt][2]+bv[nt], acc[mt][nt][3]+bv[nt]) };
        *(uint2*)&jb.C[((size_t)((m>>9)*256 + col))*512 + (m&511)] = pk;
      }
  }
}

// ---------------- MFMA GEMM with fused epilogues (single jobs) ----------------
// OUTM: 0 bf16 C[M,256] (EPI 0/1) | 3 LN(Pres+(acc+b)) -> bf16 P |
//       5 like 3 but dot outW -> fp32 logits.
template<int EPI, int OUTM>
__global__ __launch_bounds__(256,4) void k_gemm(const bf16_t* __restrict__ A,
    const bf16_t* __restrict__ Wt, const float* __restrict__ bias,
    void* __restrict__ Cv, const bf16_t* __restrict__ Pres,
    const float* __restrict__ g, const float* __restrict__ bb,
    const float* __restrict__ oW, const float* __restrict__ obp, int K)
{
  __shared__ bf16_t As[8*512];    // 8 KB
  __shared__ bf16_t Bs[32*512];   // 32 KB
  int t = threadIdx.x, w = t>>6, lane = t&63, l15 = lane&15, quad = lane>>4;
  int m0 = blockIdx.x*64;
  f32x4 z = {0.f,0.f,0.f,0.f};
  f32x4 acc[4][4] = {{z,z,z,z},{z,z,z,z},{z,z,z,z},{z,z,z,z}};

  for (int k0=0; k0<K; k0+=64){
    #pragma unroll
    for (int j=0; j<2; j++){
      int id = 2*w + j; int kc32 = id>>2, mt = id&3;
      gload16(A + (size_t)(m0 + mt*16 + l15)*K + k0 + kc32*32 + quad*8,
              &As[id*512]);
    }
    #pragma unroll
    for (int j=0; j<8; j++){
      int id = 8*w + j; int kc32 = id>>4, gnt = id&15;
      gload16(Wt + (size_t)(gnt*16 + l15)*K + k0 + kc32*32 + quad*8,
              &Bs[id*512]);
    }
    __syncthreads();
    #pragma unroll
    for (int kc=0; kc<2; kc++){
      short8 a[4], b[4];
      #pragma unroll
      for (int mt=0; mt<4; mt++) a[mt] = ld_bf8(&As[(kc*4+mt)*512 + lane*8]);
      #pragma unroll
      for (int nt=0; nt<4; nt++) b[nt] = ld_bf8(&Bs[(kc*16 + w*4 + nt)*512 + lane*8]);
      #pragma unroll
      for (int mt=0; mt<4; mt++)
        #pragma unroll
        for (int nt=0; nt<4; nt++)
          acc[mt][nt] = __builtin_amdgcn_mfma_f32_16x16x32_bf16(a[mt], b[nt], acc[mt][nt], 0,0,0);
    }
    __syncthreads();
  }

  float bv[4];
  #pragma unroll
  for (int nt=0; nt<4; nt++) bv[nt] = bias[w*64 + nt*16 + l15];

  if (OUTM==0){
    #pragma unroll
    for (int mt=0; mt<4; mt++)
      #pragma unroll
      for (int nt=0; nt<4; nt++)
        #pragma unroll
        for (int r=0; r<4; r++){
          int row = m0 + mt*16 + quad*4 + r;
          int col = w*64 + nt*16 + l15;
          float v = acc[mt][nt][r] + bv[nt];
          if (EPI==1) v = gelu_f(v);
          ((bf16_t*)Cv)[(size_t)row*256 + col] = f2bf(v);
        }
  } else {
    float* RedS = (float*)As;          // [64][4]
    float* RedQ = RedS + 256;          // [64][4]
    #pragma unroll
    for (int mt=0; mt<4; mt++)
      #pragma unroll
      for (int r=0; r<4; r++){
        int row = m0 + mt*16 + quad*4 + r;
        const bf16_t* pr = Pres + (size_t)row*256;
        float s = 0.f, q = 0.f;
        #pragma unroll
        for (int nt=0; nt<4; nt++){
          float v = acc[mt][nt][r] + bv[nt] + bf2f(pr[w*64 + nt*16 + l15]);
          s += v; q += v*v;
        }
        s += __shfl_xor(s,1); s += __shfl_xor(s,2);
        s += __shfl_xor(s,4); s += __shfl_xor(s,8);
        q += __shfl_xor(q,1); q += __shfl_xor(q,2);
        q += __shfl_xor(q,4); q += __shfl_xor(q,8);
        if (l15==0){
          int rr = mt*16 + quad*4 + r;
          RedS[rr*4 + w] = s; RedQ[rr*4 + w] = q;
        }
      }
    __syncthreads();

    float gv[4], bbv[4], wv[4];
    #pragma unroll
    for (int nt=0; nt<4; nt++){ gv[nt] = g[w*64+nt*16+l15]; bbv[nt] = bb[w*64+nt*16+l15]; }
    if (OUTM==5)
      #pragma unroll
      for (int nt=0; nt<4; nt++) wv[nt] = oW[w*64+nt*16+l15];

    float s2p[4][4];
    #pragma unroll
    for (int mt=0; mt<4; mt++)
      #pragma unroll
      for (int r=0; r<4; r++){
        int rr = mt*16 + quad*4 + r;
        int row = m0 + rr;
        float S = RedS[rr*4+0]+RedS[rr*4+1]+RedS[rr*4+2]+RedS[rr*4+3];
        float Q = RedQ[rr*4+0]+RedQ[rr*4+1]+RedQ[rr*4+2]+RedQ[rr*4+3];
        float mean = S*(1.0f/256.0f);
        float var  = Q*(1.0f/256.0f) - mean*mean;
        float rstd = rsqrtf(var + 1e-5f);
        const bf16_t* pr = Pres + (size_t)row*256;
        if (OUTM==3){
          bf16_t* po = (bf16_t*)Cv + (size_t)row*256;
          #pragma unroll
          for (int nt=0; nt<4; nt++){
            float v = acc[mt][nt][r] + bv[nt] + bf2f(pr[w*64 + nt*16 + l15]);
            po[w*64 + nt*16 + l15] = f2bf((v-mean)*rstd*gv[nt] + bbv[nt]);
          }
        } else {
          float s2 = 0.f;
          #pragma unroll
          for (int nt=0; nt<4; nt++){
            float v = acc[mt][nt][r] + bv[nt] + bf2f(pr[w*64 + nt*16 + l15]);
            s2 += ((v-mean)*rstd*gv[nt] + bbv[nt]) * wv[nt];
          }
          s2 += __shfl_xor(s2,1); s2 += __shfl_xor(s2,2);
          s2 += __shfl_xor(s2,4); s2 += __shfl_xor(s2,8);
          s2p[mt][r] = s2;
        }
      }
    if (OUTM==5){
      __syncthreads();
      #pragma unroll
      for (int mt=0; mt<4; mt++)
        #pragma unroll
        for (int r=0; r<4; r++)
          if (l15==0) RedS[(mt*16 + quad*4 + r)*4 + w] = s2p[mt][r];
      __syncthreads();
      if (w==0){
        float S = RedS[lane*4+0]+RedS[lane*4+1]+RedS[lane*4+2]+RedS[lane*4+3];
        ((float*)Cv)[m0 + lane] = S + obp[0];
      }
    }
  }
}

// ---------------- MFMA attention: LDS-free inner loop -------------------------
// Grid (h, b, qc); wave = 2 q-tiles. S^T = mfma(aK,aQ): lane holds
// S[q=l15][key=ktile*16+quad*4+r]. PV uses zero-padded 16x16x32 MFMAs:
// A-frag = {pk(p0,p1), pk(p2,p3), 0, 0} covers keys quad*4+{0..3} at MFMA-k
// quad*8+{0..3}; B-frag = {V^T 8B at ktile*16+quad*4, 0} matches. 16 real
// keys per MFMA, no P transpose, no LDS. AO aliases Qm safely (Q preloaded).
__global__ __launch_bounds__(256) void k_attn(const bf16_t* __restrict__ Qm,
    const bf16_t* __restrict__ Km, const bf16_t* __restrict__ VT,
    const float* __restrict__ valid, bf16_t* __restrict__ AO)
{
  __shared__ float Smask[512];       // 0 or -1e10 (only LDS in kernel)
  int t = threadIdx.x, wave = t>>6, lane = t&63, l15 = lane&15, quad = lane>>4;
  int h = blockIdx.x, b = blockIdx.y, qc = blockIdx.z;
  int q0 = qc*128;
  const float scale = 0.17677669529663687f;   // 1/sqrt(32)

  Smask[t]     = (valid[b*Ss + t      ] != 0.f) ? 0.f : -1.0e10f;
  Smask[t+256] = (valid[b*Ss + t + 256] != 0.f) ? 0.f : -1.0e10f;
  __syncthreads();

  short8 aQ0 = ld_bf8(Qm + (size_t)(b*Ss + q0 + (wave*2  )*16 + l15)*256 + h*32 + quad*8);
  short8 aQ1 = ld_bf8(Qm + (size_t)(b*Ss + q0 + (wave*2+1)*16 + l15)*256 + h*32 + quad*8);
  const bf16_t* Kb = Km + (size_t)(b*Ss)*256 + h*32;     // + key*256
  const bf16_t* Vb = VT + ((size_t)b*256 + h*32)*512;    // + d*512 + key

  f32x4 z = {0.f,0.f,0.f,0.f};
  f32x4 O0[2] = {z,z}, O1[2] = {z,z};
  float ls0 = 0.f, ls1 = 0.f;        // per-lane rowsum for q=l15

  for (int kt2=0; kt2<16; kt2++){
    #pragma unroll
    for (int half=0; half<2; half++){
      int ktile = kt2*2 + half;
      short8 aK = ld_bf8(Kb + (size_t)(ktile*16 + l15)*256 + quad*8);
      f32x4 s0 = __builtin_amdgcn_mfma_f32_16x16x32_bf16(aK, aQ0, z, 0,0,0);
      f32x4 s1 = __builtin_amdgcn_mfma_f32_16x16x32_bf16(aK, aQ1, z, 0,0,0);
      float4 mb = *(const float4*)&Smask[ktile*16 + quad*4];
      float p00 = __expf(fmaf(s0[0],scale, mb.x));
      float p01 = __expf(fmaf(s0[1],scale, mb.y));
      float p02 = __expf(fmaf(s0[2],scale, mb.z));
      float p03 = __expf(fmaf(s0[3],scale, mb.w));
      float p10 = __expf(fmaf(s1[0],scale, mb.x));
      float p11 = __expf(fmaf(s1[1],scale, mb.y));
      float p12 = __expf(fmaf(s1[2],scale, mb.z));
      float p13 = __expf(fmaf(s1[3],scale, mb.w));
      ls0 += (p00+p01)+(p02+p03);
      ls1 += (p10+p11)+(p12+p13);
      union { unsigned u[4]; short8 s8; } A0, A1;
      A0.u[0] = pk_bf16(p00,p01); A0.u[1] = pk_bf16(p02,p03); A0.u[2] = 0; A0.u[3] = 0;
      A1.u[0] = pk_bf16(p10,p11); A1.u[1] = pk_bf16(p12,p13); A1.u[2] = 0; A1.u[3] = 0;
      #pragma unroll
      for (int nt=0; nt<2; nt++){
        union { unsigned u[4]; short8 s8; } Bv;
        uint2 v8 = *(const uint2*)(Vb + (size_t)(nt*16+l15)*512 + ktile*16 + quad*4);
        Bv.u[0] = v8.x; Bv.u[1] = v8.y; Bv.u[2] = 0; Bv.u[3] = 0;
        O0[nt] = __builtin_amdgcn_mfma_f32_16x16x32_bf16(A0.s8, Bv.s8, O0[nt], 0,0,0);
        O1[nt] = __builtin_amdgcn_mfma_f32_16x16x32_bf16(A1.s8, Bv.s8, O1[nt], 0,0,0);
      }
    }
  }

  // rowsum reduce across quads (lanes 16 apart share q=l15)
  ls0 += __shfl_xor(ls0,16); ls0 += __shfl_xor(ls0,32);
  ls1 += __shfl_xor(ls1,16); ls1 += __shfl_xor(ls1,32);
  float linv0 = (ls0 > 0.f) ? 1.0f/ls0 : 0.f;
  float linv1 = (ls1 > 0.f) ? 1.0f/ls1 : 0.f;
  float i0[4], i1[4];
  #pragma unroll
  for (int r=0; r<4; r++){
    i0[r] = __shfl(linv0, quad*4 + r);   // lane quad*4+r has l15 == output row
    i1[r] = __shfl(linv1, quad*4 + r);
  }
  size_t r0 = (size_t)(b*Ss + q0 + (wave*2  )*16);
  size_t r1 = (size_t)(b*Ss + q0 + (wave*2+1)*16);
  #pragma unroll
  for (int nt=0; nt<2; nt++)
    #pragma unroll
    for (int r=0; r<4; r++){
      AO[(r0 + quad*4 + r)*256 + h*32 + nt*16 + l15] = f2bf(O0[nt][r]*i0[r]);
      AO[(r1 + quad*4 + r)*256 + h*32 + nt*16 + l15] = f2bf(O1[nt][r]*i1[r]);
    }
}

// ---------------- final: p = exp(logits)*valid, normalize per batch -----------
__global__ __launch_bounds__(256) void k_final(const float* __restrict__ L,
    const float* __restrict__ valid, float* __restrict__ out)
{
  __shared__ float wsum[4];
  int b = blockIdx.x, t = threadIdx.x;
  float e0 = __expf(L[b*Ss + t      ]) * valid[b*Ss + t      ];
  float e1 = __expf(L[b*Ss + 256 + t]) * valid[b*Ss + 256 + t];
  float s = e0 + e1;
  #pragma unroll
  for (int o=32;o>0;o>>=1) s += __shfl_xor(s,o);
  if ((t&63)==0) wsum[t>>6] = s;
  __syncthreads();
  float tot = wsum[0]+wsum[1]+wsum[2]+wsum[3];
  out[b*Ss + t      ] = e0/tot;
  out[b*Ss + 256 + t] = e1/tot;
}

// ============================================================================
extern "C" void kernel_launch(void* const* d_in, const int* in_sizes, int n_in,
                              void* d_out, int out_size, void* d_ws, size_t ws_size,
                              hipStream_t stream)
{
  #define F(i) ((const float*)d_in[(i)])
  bool sig = (in_sizes[33] == 256);   // signature order vs dict order
  const float* d_eqW  = F(sig?35:33); const float* d_eqb  = F(sig?36:34);
  const float* d_ekW  = F(sig?37:35); const float* d_ekb  = F(sig?38:36);
  const float* d_evW  = F(sig?39:37); const float* d_evb  = F(sig?40:38);
  const float* d_eoW  = F(sig?41:39); const float* d_eob  = F(sig?42:40);
  const float* d_ln1g = F(sig?33:41); const float* d_ln1b = F(sig?34:42);

  // ---- workspace (~163 MiB) ----
  char* w = (char*)d_ws;
  bf16_t* P0 = (bf16_t*)w; w += (size_t)Mm*Hh*2;   // 32 MiB residual (enc)
  bf16_t* P1 = (bf16_t*)w; w += (size_t)Mm*Hh*2;   // 32 MiB residual (dec)
  bf16_t* H0 = (bf16_t*)w; w += (size_t)Mm*Hh*2;   // 32 MiB Q / AO / gelu
  bf16_t* H1 = (bf16_t*)w;                          // 32 MiB K / xs alias
  bf16_t* xs = (bf16_t*)w; w += (size_t)Mm*Hh*2;
  bf16_t* H2 = (bf16_t*)w;                          // 32 MiB VT / xt alias
  bf16_t* xt = (bf16_t*)w; w += (size_t)Mm*Hh*2;
  bf16_t* Wa = (bf16_t*)w; w += (size_t)(2*16384 + 16*65536)*2;  // 2.1 MiB
  float*  valid  = (float*)w; w += (size_t)Mm*4;
  float*  logits = (float*)w; w += (size_t)Mm*4;
  float* out = (float*)d_out;

  unsigned o_sem = 0, o_tem = 16384;
  unsigned o_w[16]; for (int i=0;i<16;i++) o_w[i] = 32768 + i*65536u;
  Prep18 pp;
  const float* srcs[18] = { F(5), F(7), F(9), F(11), F(13), F(15), F(19), F(21),
                            F(25), F(27), F(29), F(31), d_eqW, d_ekW, d_evW, d_eoW,
                            F(45), F(47) };
  unsigned offs[18] = { o_sem, o_tem, o_w[0],o_w[1],o_w[2],o_w[3],o_w[4],o_w[5],
                        o_w[6],o_w[7],o_w[8],o_w[9],o_w[10],o_w[11],o_w[12],o_w[13],
                        o_w[14],o_w[15] };
  for (int i=0;i<18;i++){ pp.d[i].s = srcs[i]; pp.d[i].off = offs[i]; pp.d[i].K = (i<2)?64:256; }

  dim3 blk(256);
  dim3 gLN(Mm/4);
  dim3 gG(Mm/64);
  dim3 gA(NHh, Bb, 4);
  dim3 gP(256, 18);
  const float* NF = nullptr; const bf16_t* NB = nullptr;

  k_prep<<<gP, blk, 0, stream>>>(pp, Wa);
  k_ln0<<<gLN, blk, 0, stream>>>(F(0), F(1),F(2), F(3),F(4), xs, xt, valid);

  auto J = [](const bf16_t* A, const bf16_t* Wt, const float* bias, bf16_t* C, int outm){
    GemmJob j; j.A=A; j.Wt=Wt; j.bias=bias; j.C=C; j.outm=outm; return j;
  };

  // emb pair (independent)
  {
    GemmJobs js; js.j[0] = J(xs, Wa+o_sem, F(6), P0, 0);
    js.j[1] = J(xt, Wa+o_tem, F(8), P1, 0); js.j[2] = js.j[0];
    k_gemm3<<<dim3(Mm/64,2), blk, 0, stream>>>(js, 64);
  }

  // ---- encoder ----
  {
    GemmJobs js; js.j[0] = J(P0, Wa+o_w[0], F(10), H0, 0);
    js.j[1] = J(P0, Wa+o_w[1], F(12), H1, 0);
    js.j[2] = J(P0, Wa+o_w[2], F(14), H2, 2);
    k_gemm3<<<dim3(Mm/64,3), blk, 0, stream>>>(js, 256);
  }
  k_attn<<<gA, blk, 0, stream>>>(H0, H1, H2, valid, H0);
  k_gemm<0,3><<<gG, blk, 0, stream>>>(H0, Wa+o_w[3], F(16), P0, P0, F(17),F(18), NF,NF, 256);
  k_gemm<1,0><<<gG, blk, 0, stream>>>(P0, Wa+o_w[4], F(20), H0, NB,NF,NF,NF,NF, 256);
  k_gemm<0,3><<<gG, blk, 0, stream>>>(H0, Wa+o_w[5], F(22), P0, P0, F(23),F(24), NF,NF, 256);

  // ---- decoder self-attention ----
  {
    GemmJobs js; js.j[0] = J(P1, Wa+o_w[6], F(26), H0, 0);
    js.j[1] = J(P1, Wa+o_w[7], F(28), H1, 0);
    js.j[2] = J(P1, Wa+o_w[8], F(30), H2, 2);
    k_gemm3<<<dim3(Mm/64,3), blk, 0, stream>>>(js, 256);
  }
  k_attn<<<gA, blk, 0, stream>>>(H0, H1, H2, valid, H0);
  k_gemm<0,3><<<gG, blk, 0, stream>>>(H0, Wa+o_w[9], F(32), P1, P1, d_ln1g,d_ln1b, NF,NF, 256);

  // ---- decoder cross-attention (Q from P1; K,V from P0) ----
  {
    GemmJobs js; js.j[0] = J(P1, Wa+o_w[10], d_eqb, H0, 0);
    js.j[1] = J(P0, Wa+o_w[11], d_ekb, H1, 0);
    js.j[2] = J(P0, Wa+o_w[12], d_evb, H2, 2);
    k_gemm3<<<dim3(Mm/64,3), blk, 0, stream>>>(js, 256);
  }
  k_attn<<<gA, blk, 0, stream>>>(H0, H1, H2, valid, H0);
  k_gemm<0,3><<<gG, blk, 0, stream>>>(H0, Wa+o_w[13], d_eob, P1, P1, F(43),F(44), NF,NF, 256);

  // ---- decoder FFN + fused ln3 + logits ----
  k_gemm<1,0><<<gG, blk, 0, stream>>>(P1, Wa+o_w[14], F(46), H0, NB,NF,NF,NF,NF, 256);
  k_gemm<0,5><<<gG, blk, 0, stream>>>(H0, Wa+o_w[15], F(48), logits, P1, F(49),F(50), F(51),F(52), 256);

  k_final<<<dim3(Bb), blk, 0, stream>>>(logits, valid, out);
  #undef F
}

// Round 12
// 1095.041 us; speedup vs baseline: 1.0905x; 1.0905x over previous
//
#include <hip/hip_runtime.h>
#include <hip/hip_bf16.h>

// ============================================================================
// TransformerChoiceNet forward. Round 12: key-split attention — block =
// (b,h,32 q-rows); each of 4 waves processes the same 2 q-tiles over a
// PRIVATE 128-key range (4 kt2 iters, was 16 -> 4x shorter serial chain),
// partial O/l reduced across waves via LDS (overlaid on dead Pbuf/Smask).
// Inner loop = r10's proven form (single-slot Pbuf, 16B K/V, native exp).
// GEMMs unchanged from r10/r11 (incl. fast gelu).
// B=128 S=512 D=64 H=256 NH=8 HD=32, M=B*S=65536.
// ============================================================================

#define Bb  128
#define Ss  512
#define Hh  256
#define NHh 8
#define Mm  (Bb*Ss)

typedef unsigned short bf16_t;
typedef __attribute__((ext_vector_type(8))) short short8;
typedef __attribute__((ext_vector_type(4))) float f32x4;

__device__ __forceinline__ float bf2f(bf16_t h){
  union { unsigned int u; float f; } v; v.u = ((unsigned int)h)<<16; return v.f;
}
__device__ __forceinline__ bf16_t f2bf(float f){
  union { float f; unsigned int u; } v; v.f = f;
  unsigned int r = (v.u + 0x7fffu + ((v.u>>16)&1u)) >> 16;   // RNE
  return (bf16_t)r;
}
__device__ __forceinline__ unsigned pk_bf16(float a, float b){  // packed RNE cvt
  union { __hip_bfloat162 h; unsigned u; } v;
  v.h = __float22bfloat162_rn(float2{a,b});
  return v.u;
}
__device__ __forceinline__ short8 ld_bf8(const bf16_t* p){   // 16B load
  union { uint4 u; short8 s; } v; v.u = *(const uint4*)p; return v.s;
}
__device__ __forceinline__ void gload16(const bf16_t* g, bf16_t* l){
  __builtin_amdgcn_global_load_lds(
      (const __attribute__((address_space(1))) void*)g,
      (__attribute__((address_space(3))) void*)l, 16, 0, 0);
}
__device__ __forceinline__ float gelu_f(float x){
  // NewGELU; tanh via native exp + rcp: tanh(u) = 1 - 2/(e^{2u}+1)
  float u = 0.7978845608028654f*(x + 0.044715f*x*x*x);
  float e = __expf(2.0f*u);
  float th = 1.0f - 2.0f*__builtin_amdgcn_rcpf(e + 1.0f);
  return 0.5f*x*(1.0f + th);
}

// ---------------- weight prep: fp32 W[k][n] -> bf16 Wt[n][k] ------------------
struct PrepDesc { const float* s; unsigned off; int K; };
struct Prep18  { PrepDesc d[18]; };

__global__ __launch_bounds__(256) void k_prep(Prep18 p, bf16_t* __restrict__ arena)
{
  PrepDesc dd = p.d[blockIdx.y];
  int i = blockIdx.x*256 + threadIdx.x;
  if (i < dd.K*256){
    int k = i>>8, n = i&255;
    arena[dd.off + n*dd.K + k] = f2bf(dd.s[i]);
  }
}

// ---------------- LN0 (two gains) + valid mask; bf16 out ----------------------
__global__ __launch_bounds__(256) void k_ln0(const float* __restrict__ src,
    const float* __restrict__ gs, const float* __restrict__ bs,
    const float* __restrict__ gt, const float* __restrict__ bt,
    bf16_t* __restrict__ xs, bf16_t* __restrict__ xt, float* __restrict__ valid)
{
  int row  = blockIdx.x*4 + (threadIdx.x>>6);
  int lane = threadIdx.x & 63;
  float x = src[(size_t)row*64 + lane];
  float s = x;
  #pragma unroll
  for (int o=32;o>0;o>>=1) s += __shfl_xor(s,o);
  float mean = s*(1.0f/64.0f);
  float d = x - mean;
  float ss = d*d;
  #pragma unroll
  for (int o=32;o>0;o>>=1) ss += __shfl_xor(ss,o);
  float r = rsqrtf(ss*(1.0f/64.0f) + 1e-5f);
  float xn = d*r;
  xs[(size_t)row*64+lane] = f2bf(xn*gs[lane] + bs[lane]);
  xt[(size_t)row*64+lane] = f2bf(xn*gt[lane] + bt[lane]);
  if (lane==0) valid[row] = (s != 0.0f) ? 1.0f : 0.0f;
}

// ---------------- merged independent GEMMs (QKV trio / emb pair) --------------
struct GemmJob  { const bf16_t* A; const bf16_t* Wt; const float* bias; bf16_t* C; int outm; };
struct GemmJobs { GemmJob j[3]; };

__global__ __launch_bounds__(256,4) void k_gemm3(GemmJobs jobs, int K)
{
  __shared__ bf16_t As[8*512];    // 8 KB
  __shared__ bf16_t Bs[32*512];   // 32 KB
  GemmJob jb = jobs.j[blockIdx.y];
  int t = threadIdx.x, w = t>>6, lane = t&63, l15 = lane&15, quad = lane>>4;
  int m0 = blockIdx.x*64;
  f32x4 z = {0.f,0.f,0.f,0.f};
  f32x4 acc[4][4] = {{z,z,z,z},{z,z,z,z},{z,z,z,z},{z,z,z,z}};

  for (int k0=0; k0<K; k0+=64){
    #pragma unroll
    for (int j=0; j<2; j++){
      int id = 2*w + j; int kc32 = id>>2, mt = id&3;
      gload16(jb.A + (size_t)(m0 + mt*16 + l15)*K + k0 + kc32*32 + quad*8,
              &As[id*512]);
    }
    #pragma unroll
    for (int j=0; j<8; j++){
      int id = 8*w + j; int kc32 = id>>4, gnt = id&15;
      gload16(jb.Wt + (size_t)(gnt*16 + l15)*K + k0 + kc32*32 + quad*8,
              &Bs[id*512]);
    }
    __syncthreads();
    #pragma unroll
    for (int kc=0; kc<2; kc++){
      short8 a[4], b[4];
      #pragma unroll
      for (int mt=0; mt<4; mt++) a[mt] = ld_bf8(&As[(kc*4+mt)*512 + lane*8]);
      #pragma unroll
      for (int nt=0; nt<4; nt++) b[nt] = ld_bf8(&Bs[(kc*16 + w*4 + nt)*512 + lane*8]);
      #pragma unroll
      for (int mt=0; mt<4; mt++)
        #pragma unroll
        for (int nt=0; nt<4; nt++)
          acc[mt][nt] = __builtin_amdgcn_mfma_f32_16x16x32_bf16(a[mt], b[nt], acc[mt][nt], 0,0,0);
    }
    __syncthreads();
  }

  float bv[4];
  #pragma unroll
  for (int nt=0; nt<4; nt++) bv[nt] = jb.bias[w*64 + nt*16 + l15];

  if (jb.outm == 0){
    #pragma unroll
    for (int mt=0; mt<4; mt++)
      #pragma unroll
      for (int nt=0; nt<4; nt++){
        int m = m0 + mt*16 + quad*4;
        int col = w*64 + nt*16 + l15;
        #pragma unroll
        for (int r=0; r<4; r++)
          jb.C[(size_t)(m+r)*256 + col] = f2bf(acc[mt][nt][r] + bv[nt]);
      }
  } else {
    #pragma unroll
    for (int mt=0; mt<4; mt++)
      #pragma unroll
      for (int nt=0; nt<4; nt++){
        int m = m0 + mt*16 + quad*4;
        int col = w*64 + nt*16 + l15;
        uint2 pk = { pk_bf16(acc[mt][nt][0]+bv[nt], acc[mt][nt][1]+bv[nt]),
                     pk_bf16(acc[mt][nt][2]+bv[nt], acc[mt][nt][3]+bv[nt]) };
        *(uint2*)&jb.C[((size_t)((m>>9)*256 + col))*512 + (m&511)] = pk;
      }
  }
}

// ---------------- MFMA GEMM with fused epilogues (single jobs) ----------------
template<int EPI, int OUTM>
__global__ __launch_bounds__(256,4) void k_gemm(const bf16_t* __restrict__ A,
    const bf16_t* __restrict__ Wt, const float* __restrict__ bias,
    void* __restrict__ Cv, const bf16_t* __restrict__ Pres,
    const float* __restrict__ g, const float* __restrict__ bb,
    const float* __restrict__ oW, const float* __restrict__ obp, int K)
{
  __shared__ bf16_t As[8*512];    // 8 KB
  __shared__ bf16_t Bs[32*512];   // 32 KB
  int t = threadIdx.x, w = t>>6, lane = t&63, l15 = lane&15, quad = lane>>4;
  int m0 = blockIdx.x*64;
  f32x4 z = {0.f,0.f,0.f,0.f};
  f32x4 acc[4][4] = {{z,z,z,z},{z,z,z,z},{z,z,z,z},{z,z,z,z}};

  for (int k0=0; k0<K; k0+=64){
    #pragma unroll
    for (int j=0; j<2; j++){
      int id = 2*w + j; int kc32 = id>>2, mt = id&3;
      gload16(A + (size_t)(m0 + mt*16 + l15)*K + k0 + kc32*32 + quad*8,
              &As[id*512]);
    }
    #pragma unroll
    for (int j=0; j<8; j++){
      int id = 8*w + j; int kc32 = id>>4, gnt = id&15;
      gload16(Wt + (size_t)(gnt*16 + l15)*K + k0 + kc32*32 + quad*8,
              &Bs[id*512]);
    }
    __syncthreads();
    #pragma unroll
    for (int kc=0; kc<2; kc++){
      short8 a[4], b[4];
      #pragma unroll
      for (int mt=0; mt<4; mt++) a[mt] = ld_bf8(&As[(kc*4+mt)*512 + lane*8]);
      #pragma unroll
      for (int nt=0; nt<4; nt++) b[nt] = ld_bf8(&Bs[(kc*16 + w*4 + nt)*512 + lane*8]);
      #pragma unroll
      for (int mt=0; mt<4; mt++)
        #pragma unroll
        for (int nt=0; nt<4; nt++)
          acc[mt][nt] = __builtin_amdgcn_mfma_f32_16x16x32_bf16(a[mt], b[nt], acc[mt][nt], 0,0,0);
    }
    __syncthreads();
  }

  float bv[4];
  #pragma unroll
  for (int nt=0; nt<4; nt++) bv[nt] = bias[w*64 + nt*16 + l15];

  if (OUTM==0){
    #pragma unroll
    for (int mt=0; mt<4; mt++)
      #pragma unroll
      for (int nt=0; nt<4; nt++)
        #pragma unroll
        for (int r=0; r<4; r++){
          int row = m0 + mt*16 + quad*4 + r;
          int col = w*64 + nt*16 + l15;
          float v = acc[mt][nt][r] + bv[nt];
          if (EPI==1) v = gelu_f(v);
          ((bf16_t*)Cv)[(size_t)row*256 + col] = f2bf(v);
        }
  } else {
    float* RedS = (float*)As;          // [64][4]
    float* RedQ = RedS + 256;          // [64][4]
    #pragma unroll
    for (int mt=0; mt<4; mt++)
      #pragma unroll
      for (int r=0; r<4; r++){
        int row = m0 + mt*16 + quad*4 + r;
        const bf16_t* pr = Pres + (size_t)row*256;
        float s = 0.f, q = 0.f;
        #pragma unroll
        for (int nt=0; nt<4; nt++){
          float v = acc[mt][nt][r] + bv[nt] + bf2f(pr[w*64 + nt*16 + l15]);
          s += v; q += v*v;
        }
        s += __shfl_xor(s,1); s += __shfl_xor(s,2);
        s += __shfl_xor(s,4); s += __shfl_xor(s,8);
        q += __shfl_xor(q,1); q += __shfl_xor(q,2);
        q += __shfl_xor(q,4); q += __shfl_xor(q,8);
        if (l15==0){
          int rr = mt*16 + quad*4 + r;
          RedS[rr*4 + w] = s; RedQ[rr*4 + w] = q;
        }
      }
    __syncthreads();

    float gv[4], bbv[4], wv[4];
    #pragma unroll
    for (int nt=0; nt<4; nt++){ gv[nt] = g[w*64+nt*16+l15]; bbv[nt] = bb[w*64+nt*16+l15]; }
    if (OUTM==5)
      #pragma unroll
      for (int nt=0; nt<4; nt++) wv[nt] = oW[w*64+nt*16+l15];

    float s2p[4][4];
    #pragma unroll
    for (int mt=0; mt<4; mt++)
      #pragma unroll
      for (int r=0; r<4; r++){
        int rr = mt*16 + quad*4 + r;
        int row = m0 + rr;
        float S = RedS[rr*4+0]+RedS[rr*4+1]+RedS[rr*4+2]+RedS[rr*4+3];
        float Q = RedQ[rr*4+0]+RedQ[rr*4+1]+RedQ[rr*4+2]+RedQ[rr*4+3];
        float mean = S*(1.0f/256.0f);
        float var  = Q*(1.0f/256.0f) - mean*mean;
        float rstd = rsqrtf(var + 1e-5f);
        const bf16_t* pr = Pres + (size_t)row*256;
        if (OUTM==3){
          bf16_t* po = (bf16_t*)Cv + (size_t)row*256;
          #pragma unroll
          for (int nt=0; nt<4; nt++){
            float v = acc[mt][nt][r] + bv[nt] + bf2f(pr[w*64 + nt*16 + l15]);
            po[w*64 + nt*16 + l15] = f2bf((v-mean)*rstd*gv[nt] + bbv[nt]);
          }
        } else {
          float s2 = 0.f;
          #pragma unroll
          for (int nt=0; nt<4; nt++){
            float v = acc[mt][nt][r] + bv[nt] + bf2f(pr[w*64 + nt*16 + l15]);
            s2 += ((v-mean)*rstd*gv[nt] + bbv[nt]) * wv[nt];
          }
          s2 += __shfl_xor(s2,1); s2 += __shfl_xor(s2,2);
          s2 += __shfl_xor(s2,4); s2 += __shfl_xor(s2,8);
          s2p[mt][r] = s2;
        }
      }
    if (OUTM==5){
      __syncthreads();
      #pragma unroll
      for (int mt=0; mt<4; mt++)
        #pragma unroll
        for (int r=0; r<4; r++)
          if (l15==0) RedS[(mt*16 + quad*4 + r)*4 + w] = s2p[mt][r];
      __syncthreads();
      if (w==0){
        float S = RedS[lane*4+0]+RedS[lane*4+1]+RedS[lane*4+2]+RedS[lane*4+3];
        ((float*)Cv)[m0 + lane] = S + obp[0];
      }
    }
  }
}

// ---------------- MFMA attention: key-split across waves ----------------------
// Grid (h, qc, b): block = 32 q-rows (2 q-tiles, shared by all 4 waves);
// wave w covers keys [w*128, w*128+128) -> 4 kt2 iterations (serial chain /4).
// Unnormalized softmax sums are linear: partial O and l reduced across waves
// via LDS (Ored overlays dead Pbuf+Smask after a barrier).
// S^T = mfma(aK,aQ): lane holds S[q=l15][key=ktile*16+quad*4+r].
__global__ __launch_bounds__(256) void k_attn(const bf16_t* __restrict__ Qm,
    const bf16_t* __restrict__ Km, const bf16_t* __restrict__ VT,
    const float* __restrict__ valid, bf16_t* __restrict__ AO)
{
  __shared__ __align__(16) char LDSm[16896];
  bf16_t (*Pbuf)[2][16][40] = (bf16_t(*)[2][16][40])LDSm;   // [4][2][16][40] 10.2 KB
  float* Smask = (float*)(LDSm + 10240);                    // [512] 2 KB
  float* Ored  = (float*)LDSm;                              // [4][4][64][4] 16 KB (epi)
  float* lsred = (float*)(LDSm + 16384);                    // [8][16] 512 B (epi)

  int t = threadIdx.x, wave = t>>6, lane = t&63, l15 = lane&15, quad = lane>>4;
  int h = blockIdx.x, qc = blockIdx.y, b = blockIdx.z;
  int q0 = qc*32;
  const float scale = 0.17677669529663687f;   // 1/sqrt(32)

  Smask[t]     = (valid[b*Ss + t      ] != 0.f) ? 0.f : -1.0e10f;
  Smask[t+256] = (valid[b*Ss + t + 256] != 0.f) ? 0.f : -1.0e10f;
  __syncthreads();

  // all waves load the SAME 2 q-tiles (L1 broadcast)
  short8 aQ0 = ld_bf8(Qm + (size_t)(b*Ss + q0      + l15)*256 + h*32 + quad*8);
  short8 aQ1 = ld_bf8(Qm + (size_t)(b*Ss + q0 + 16 + l15)*256 + h*32 + quad*8);
  const bf16_t* Kb = Km + (size_t)(b*Ss)*256 + h*32;     // + key*256
  const bf16_t* Vb = VT + ((size_t)b*256 + h*32)*512;    // + d*512 + key

  f32x4 z = {0.f,0.f,0.f,0.f};
  f32x4 O0[2] = {z,z}, O1[2] = {z,z};
  float ls0 = 0.f, ls1 = 0.f;

  for (int kt2=0; kt2<4; kt2++){
    #pragma unroll
    for (int half=0; half<2; half++){
      int ktile = wave*8 + kt2*2 + half;
      short8 aK = ld_bf8(Kb + (size_t)(ktile*16 + l15)*256 + quad*8);
      f32x4 s0 = __builtin_amdgcn_mfma_f32_16x16x32_bf16(aK, aQ0, z, 0,0,0);
      f32x4 s1 = __builtin_amdgcn_mfma_f32_16x16x32_bf16(aK, aQ1, z, 0,0,0);
      float4 mb = *(const float4*)&Smask[ktile*16 + quad*4];
      float p00 = __expf(fmaf(s0[0],scale, mb.x));
      float p01 = __expf(fmaf(s0[1],scale, mb.y));
      float p02 = __expf(fmaf(s0[2],scale, mb.z));
      float p03 = __expf(fmaf(s0[3],scale, mb.w));
      float p10 = __expf(fmaf(s1[0],scale, mb.x));
      float p11 = __expf(fmaf(s1[1],scale, mb.y));
      float p12 = __expf(fmaf(s1[2],scale, mb.z));
      float p13 = __expf(fmaf(s1[3],scale, mb.w));
      ls0 += (p00+p01)+(p02+p03);
      ls1 += (p10+p11)+(p12+p13);
      uint2 w0 = { pk_bf16(p00,p01), pk_bf16(p02,p03) };
      uint2 w1 = { pk_bf16(p10,p11), pk_bf16(p12,p13) };
      *(uint2*)&Pbuf[wave][0][l15][half*16 + quad*4] = w0;
      *(uint2*)&Pbuf[wave][1][l15][half*16 + quad*4] = w1;
    }
    short8 aP0 = ld_bf8(&Pbuf[wave][0][l15][quad*8]);   // A[m=q][k=key-in-range]
    short8 aP1 = ld_bf8(&Pbuf[wave][1][l15][quad*8]);
    #pragma unroll
    for (int nt=0; nt<2; nt++){
      short8 bV = ld_bf8(Vb + (size_t)(nt*16+l15)*512 + wave*128 + kt2*32 + quad*8);
      O0[nt] = __builtin_amdgcn_mfma_f32_16x16x32_bf16(aP0, bV, O0[nt], 0,0,0);
      O1[nt] = __builtin_amdgcn_mfma_f32_16x16x32_bf16(aP1, bV, O1[nt], 0,0,0);
    }
  }

  // intra-wave rowsum reduce (lanes 16 apart share q=l15)
  ls0 += __shfl_xor(ls0,16); ls0 += __shfl_xor(ls0,32);
  ls1 += __shfl_xor(ls1,16); ls1 += __shfl_xor(ls1,32);
  if (lane < 16){
    lsred[(wave*2+0)*16 + lane] = ls0;
    lsred[(wave*2+1)*16 + lane] = ls1;
  }
  __syncthreads();                      // all Pbuf/Smask reads done -> reuse as Ored
  *(f32x4*)&Ored[((wave*4+0)*64 + lane)*4] = O0[0];
  *(f32x4*)&Ored[((wave*4+1)*64 + lane)*4] = O0[1];
  *(f32x4*)&Ored[((wave*4+2)*64 + lane)*4] = O1[0];
  *(f32x4*)&Ored[((wave*4+3)*64 + lane)*4] = O1[1];
  __syncthreads();

  f32x4 R[4];
  #pragma unroll
  for (int rg=0; rg<4; rg++){
    f32x4 a0 = *(const f32x4*)&Ored[((0*4+rg)*64 + lane)*4];
    f32x4 a1 = *(const f32x4*)&Ored[((1*4+rg)*64 + lane)*4];
    f32x4 a2 = *(const f32x4*)&Ored[((2*4+rg)*64 + lane)*4];
    f32x4 a3 = *(const f32x4*)&Ored[((3*4+rg)*64 + lane)*4];
    #pragma unroll
    for (int r=0; r<4; r++) R[rg][r] = (a0[r]+a1[r]) + (a2[r]+a3[r]);
  }
  float l0 = (lsred[0*16+l15] + lsred[2*16+l15]) + (lsred[4*16+l15] + lsred[6*16+l15]);
  float l1 = (lsred[1*16+l15] + lsred[3*16+l15]) + (lsred[5*16+l15] + lsred[7*16+l15]);
  float linv0 = (l0 > 0.f) ? 1.0f/l0 : 0.f;
  float linv1 = (l1 > 0.f) ? 1.0f/l1 : 0.f;
  float i0[4], i1[4];
  #pragma unroll
  for (int r=0; r<4; r++){
    i0[r] = __shfl(linv0, quad*4 + r);   // lane quad*4+r holds l15 == output row
    i1[r] = __shfl(linv1, quad*4 + r);
  }
  size_t r0 = (size_t)(b*Ss + q0);
  size_t r1 = r0 + 16;
  #pragma unroll
  for (int nt=0; nt<2; nt++)
    #pragma unroll
    for (int r=0; r<4; r++){
      AO[(r0 + quad*4 + r)*256 + h*32 + nt*16 + l15] = f2bf(R[nt  ][r]*i0[r]);
      AO[(r1 + quad*4 + r)*256 + h*32 + nt*16 + l15] = f2bf(R[2+nt][r]*i1[r]);
    }
}

// ---------------- final: p = exp(logits)*valid, normalize per batch -----------
__global__ __launch_bounds__(256) void k_final(const float* __restrict__ L,
    const float* __restrict__ valid, float* __restrict__ out)
{
  __shared__ float wsum[4];
  int b = blockIdx.x, t = threadIdx.x;
  float e0 = __expf(L[b*Ss + t      ]) * valid[b*Ss + t      ];
  float e1 = __expf(L[b*Ss + 256 + t]) * valid[b*Ss + 256 + t];
  float s = e0 + e1;
  #pragma unroll
  for (int o=32;o>0;o>>=1) s += __shfl_xor(s,o);
  if ((t&63)==0) wsum[t>>6] = s;
  __syncthreads();
  float tot = wsum[0]+wsum[1]+wsum[2]+wsum[3];
  out[b*Ss + t      ] = e0/tot;
  out[b*Ss + 256 + t] = e1/tot;
}

// ============================================================================
extern "C" void kernel_launch(void* const* d_in, const int* in_sizes, int n_in,
                              void* d_out, int out_size, void* d_ws, size_t ws_size,
                              hipStream_t stream)
{
  #define F(i) ((const float*)d_in[(i)])
  bool sig = (in_sizes[33] == 256);   // signature order vs dict order
  const float* d_eqW  = F(sig?35:33); const float* d_eqb  = F(sig?36:34);
  const float* d_ekW  = F(sig?37:35); const float* d_ekb  = F(sig?38:36);
  const float* d_evW  = F(sig?39:37); const float* d_evb  = F(sig?40:38);
  const float* d_eoW  = F(sig?41:39); const float* d_eob  = F(sig?42:40);
  const float* d_ln1g = F(sig?33:41); const float* d_ln1b = F(sig?34:42);

  // ---- workspace (~163 MiB) ----
  char* w = (char*)d_ws;
  bf16_t* P0 = (bf16_t*)w; w += (size_t)Mm*Hh*2;   // 32 MiB residual (enc)
  bf16_t* P1 = (bf16_t*)w; w += (size_t)Mm*Hh*2;   // 32 MiB residual (dec)
  bf16_t* H0 = (bf16_t*)w; w += (size_t)Mm*Hh*2;   // 32 MiB Q / AO / gelu
  bf16_t* H1 = (bf16_t*)w;                          // 32 MiB K / xs alias
  bf16_t* xs = (bf16_t*)w; w += (size_t)Mm*Hh*2;
  bf16_t* H2 = (bf16_t*)w;                          // 32 MiB VT / xt alias
  bf16_t* xt = (bf16_t*)w; w += (size_t)Mm*Hh*2;
  bf16_t* Wa = (bf16_t*)w; w += (size_t)(2*16384 + 16*65536)*2;  // 2.1 MiB
  float*  valid  = (float*)w; w += (size_t)Mm*4;
  float*  logits = (float*)w; w += (size_t)Mm*4;
  float* out = (float*)d_out;

  unsigned o_sem = 0, o_tem = 16384;
  unsigned o_w[16]; for (int i=0;i<16;i++) o_w[i] = 32768 + i*65536u;
  Prep18 pp;
  const float* srcs[18] = { F(5), F(7), F(9), F(11), F(13), F(15), F(19), F(21),
                            F(25), F(27), F(29), F(31), d_eqW, d_ekW, d_evW, d_eoW,
                            F(45), F(47) };
  unsigned offs[18] = { o_sem, o_tem, o_w[0],o_w[1],o_w[2],o_w[3],o_w[4],o_w[5],
                        o_w[6],o_w[7],o_w[8],o_w[9],o_w[10],o_w[11],o_w[12],o_w[13],
                        o_w[14],o_w[15] };
  for (int i=0;i<18;i++){ pp.d[i].s = srcs[i]; pp.d[i].off = offs[i]; pp.d[i].K = (i<2)?64:256; }

  dim3 blk(256);
  dim3 gLN(Mm/4);
  dim3 gG(Mm/64);
  dim3 gA(NHh, 16, Bb);   // h fastest, qc middle (qc-sharers 8 ids apart), b slowest
  dim3 gP(256, 18);
  const float* NF = nullptr; const bf16_t* NB = nullptr;

  k_prep<<<gP, blk, 0, stream>>>(pp, Wa);
  k_ln0<<<gLN, blk, 0, stream>>>(F(0), F(1),F(2), F(3),F(4), xs, xt, valid);

  auto J = [](const bf16_t* A, const bf16_t* Wt, const float* bias, bf16_t* C, int outm){
    GemmJob j; j.A=A; j.Wt=Wt; j.bias=bias; j.C=C; j.outm=outm; return j;
  };

  // emb pair (independent)
  {
    GemmJobs js; js.j[0] = J(xs, Wa+o_sem, F(6), P0, 0);
    js.j[1] = J(xt, Wa+o_tem, F(8), P1, 0); js.j[2] = js.j[0];
    k_gemm3<<<dim3(Mm/64,2), blk, 0, stream>>>(js, 64);
  }

  // ---- encoder ----
  {
    GemmJobs js; js.j[0] = J(P0, Wa+o_w[0], F(10), H0, 0);
    js.j[1] = J(P0, Wa+o_w[1], F(12), H1, 0);
    js.j[2] = J(P0, Wa+o_w[2], F(14), H2, 2);
    k_gemm3<<<dim3(Mm/64,3), blk, 0, stream>>>(js, 256);
  }
  k_attn<<<gA, blk, 0, stream>>>(H0, H1, H2, valid, H0);
  k_gemm<0,3><<<gG, blk, 0, stream>>>(H0, Wa+o_w[3], F(16), P0, P0, F(17),F(18), NF,NF, 256);
  k_gemm<1,0><<<gG, blk, 0, stream>>>(P0, Wa+o_w[4], F(20), H0, NB,NF,NF,NF,NF, 256);
  k_gemm<0,3><<<gG, blk, 0, stream>>>(H0, Wa+o_w[5], F(22), P0, P0, F(23),F(24), NF,NF, 256);

  // ---- decoder self-attention ----
  {
    GemmJobs js; js.j[0] = J(P1, Wa+o_w[6], F(26), H0, 0);
    js.j[1] = J(P1, Wa+o_w[7], F(28), H1, 0);
    js.j[2] = J(P1, Wa+o_w[8], F(30), H2, 2);
    k_gemm3<<<dim3(Mm/64,3), blk, 0, stream>>>(js, 256);
  }
  k_attn<<<gA, blk, 0, stream>>>(H0, H1, H2, valid, H0);
  k_gemm<0,3><<<gG, blk, 0, stream>>>(H0, Wa+o_w[9], F(32), P1, P1, d_ln1g,d_ln1b, NF,NF, 256);

  // ---- decoder cross-attention (Q from P1; K,V from P0) ----
  {
    GemmJobs js; js.j[0] = J(P1, Wa+o_w[10], d_eqb, H0, 0);
    js.j[1] = J(P0, Wa+o_w[11], d_ekb, H1, 0);
    js.j[2] = J(P0, Wa+o_w[12], d_evb, H2, 2);
    k_gemm3<<<dim3(Mm/64,3), blk, 0, stream>>>(js, 256);
  }
  k_attn<<<gA, blk, 0, stream>>>(H0, H1, H2, valid, H0);
  k_gemm<0,3><<<gG, blk, 0, stream>>>(H0, Wa+o_w[13], d_eob, P1, P1, F(43),F(44), NF,NF, 256);

  // ---- decoder FFN + fused ln3 + logits ----
  k_gemm<1,0><<<gG, blk, 0, stream>>>(P1, Wa+o_w[14], F(46), H0, NB,NF,NF,NF,NF, 256);
  k_gemm<0,5><<<gG, blk, 0, stream>>>(H0, Wa+o_w[15], F(48), logits, P1, F(49),F(50), F(51),F(52), 256);

  k_final<<<dim3(Bb), blk, 0, stream>>>(logits, valid, out);
  #undef F
}

// Round 13
// 1029.235 us; speedup vs baseline: 1.1603x; 1.0639x over previous
//
#include <hip/hip_runtime.h>
#include <hip/hip_bf16.h>

// ============================================================================
// TransformerChoiceNet forward. Round 13: attention reverted to r10's measured
// best (1-iter lookahead pipeline, grid (h,b,qc)); softmax scale folded into
// the Q-projection GEMM epilogue (cscale) so attn exp arg is add-only.
// GEMMs otherwise unchanged (fast gelu kept).
// B=128 S=512 D=64 H=256 NH=8 HD=32, M=B*S=65536.
// ============================================================================

#define Bb  128
#define Ss  512
#define Hh  256
#define NHh 8
#define Mm  (Bb*Ss)

typedef unsigned short bf16_t;
typedef __attribute__((ext_vector_type(8))) short short8;
typedef __attribute__((ext_vector_type(4))) float f32x4;

__device__ __forceinline__ float bf2f(bf16_t h){
  union { unsigned int u; float f; } v; v.u = ((unsigned int)h)<<16; return v.f;
}
__device__ __forceinline__ bf16_t f2bf(float f){
  union { float f; unsigned int u; } v; v.f = f;
  unsigned int r = (v.u + 0x7fffu + ((v.u>>16)&1u)) >> 16;   // RNE
  return (bf16_t)r;
}
__device__ __forceinline__ unsigned pk_bf16(float a, float b){  // packed RNE cvt
  union { __hip_bfloat162 h; unsigned u; } v;
  v.h = __float22bfloat162_rn(float2{a,b});
  return v.u;
}
__device__ __forceinline__ short8 ld_bf8(const bf16_t* p){   // 16B load
  union { uint4 u; short8 s; } v; v.u = *(const uint4*)p; return v.s;
}
__device__ __forceinline__ void gload16(const bf16_t* g, bf16_t* l){
  __builtin_amdgcn_global_load_lds(
      (const __attribute__((address_space(1))) void*)g,
      (__attribute__((address_space(3))) void*)l, 16, 0, 0);
}
__device__ __forceinline__ float gelu_f(float x){
  // NewGELU; tanh via native exp + rcp: tanh(u) = 1 - 2/(e^{2u}+1)
  float u = 0.7978845608028654f*(x + 0.044715f*x*x*x);
  float e = __expf(2.0f*u);
  float th = 1.0f - 2.0f*__builtin_amdgcn_rcpf(e + 1.0f);
  return 0.5f*x*(1.0f + th);
}

// ---------------- weight prep: fp32 W[k][n] -> bf16 Wt[n][k] ------------------
struct PrepDesc { const float* s; unsigned off; int K; };
struct Prep18  { PrepDesc d[18]; };

__global__ __launch_bounds__(256) void k_prep(Prep18 p, bf16_t* __restrict__ arena)
{
  PrepDesc dd = p.d[blockIdx.y];
  int i = blockIdx.x*256 + threadIdx.x;
  if (i < dd.K*256){
    int k = i>>8, n = i&255;
    arena[dd.off + n*dd.K + k] = f2bf(dd.s[i]);
  }
}

// ---------------- LN0 (two gains) + valid mask; bf16 out ----------------------
__global__ __launch_bounds__(256) void k_ln0(const float* __restrict__ src,
    const float* __restrict__ gs, const float* __restrict__ bs,
    const float* __restrict__ gt, const float* __restrict__ bt,
    bf16_t* __restrict__ xs, bf16_t* __restrict__ xt, float* __restrict__ valid)
{
  int row  = blockIdx.x*4 + (threadIdx.x>>6);
  int lane = threadIdx.x & 63;
  float x = src[(size_t)row*64 + lane];
  float s = x;
  #pragma unroll
  for (int o=32;o>0;o>>=1) s += __shfl_xor(s,o);
  float mean = s*(1.0f/64.0f);
  float d = x - mean;
  float ss = d*d;
  #pragma unroll
  for (int o=32;o>0;o>>=1) ss += __shfl_xor(ss,o);
  float r = rsqrtf(ss*(1.0f/64.0f) + 1e-5f);
  float xn = d*r;
  xs[(size_t)row*64+lane] = f2bf(xn*gs[lane] + bs[lane]);
  xt[(size_t)row*64+lane] = f2bf(xn*gt[lane] + bt[lane]);
  if (lane==0) valid[row] = (s != 0.0f) ? 1.0f : 0.0f;
}

// ---------------- merged independent GEMMs (QKV trio / emb pair) --------------
// blockIdx.y selects job. outm: 0 = bf16 C[M,256], 2 = bf16 VT[b][n][s].
// cs: epilogue scale (Q projection carries 1/sqrt(HD) so attn skips the fma).
struct GemmJob  { const bf16_t* A; const bf16_t* Wt; const float* bias; bf16_t* C;
                  int outm; float cs; };
struct GemmJobs { GemmJob j[3]; };

__global__ __launch_bounds__(256,4) void k_gemm3(GemmJobs jobs, int K)
{
  __shared__ bf16_t As[8*512];    // 8 KB
  __shared__ bf16_t Bs[32*512];   // 32 KB
  GemmJob jb = jobs.j[blockIdx.y];
  int t = threadIdx.x, w = t>>6, lane = t&63, l15 = lane&15, quad = lane>>4;
  int m0 = blockIdx.x*64;
  f32x4 z = {0.f,0.f,0.f,0.f};
  f32x4 acc[4][4] = {{z,z,z,z},{z,z,z,z},{z,z,z,z},{z,z,z,z}};

  for (int k0=0; k0<K; k0+=64){
    #pragma unroll
    for (int j=0; j<2; j++){
      int id = 2*w + j; int kc32 = id>>2, mt = id&3;
      gload16(jb.A + (size_t)(m0 + mt*16 + l15)*K + k0 + kc32*32 + quad*8,
              &As[id*512]);
    }
    #pragma unroll
    for (int j=0; j<8; j++){
      int id = 8*w + j; int kc32 = id>>4, gnt = id&15;
      gload16(jb.Wt + (size_t)(gnt*16 + l15)*K + k0 + kc32*32 + quad*8,
              &Bs[id*512]);
    }
    __syncthreads();
    #pragma unroll
    for (int kc=0; kc<2; kc++){
      short8 a[4], b[4];
      #pragma unroll
      for (int mt=0; mt<4; mt++) a[mt] = ld_bf8(&As[(kc*4+mt)*512 + lane*8]);
      #pragma unroll
      for (int nt=0; nt<4; nt++) b[nt] = ld_bf8(&Bs[(kc*16 + w*4 + nt)*512 + lane*8]);
      #pragma unroll
      for (int mt=0; mt<4; mt++)
        #pragma unroll
        for (int nt=0; nt<4; nt++)
          acc[mt][nt] = __builtin_amdgcn_mfma_f32_16x16x32_bf16(a[mt], b[nt], acc[mt][nt], 0,0,0);
    }
    __syncthreads();
  }

  float bv[4];
  #pragma unroll
  for (int nt=0; nt<4; nt++) bv[nt] = jb.bias[w*64 + nt*16 + l15];
  float cs = jb.cs;

  if (jb.outm == 0){
    #pragma unroll
    for (int mt=0; mt<4; mt++)
      #pragma unroll
      for (int nt=0; nt<4; nt++){
        int m = m0 + mt*16 + quad*4;
        int col = w*64 + nt*16 + l15;
        #pragma unroll
        for (int r=0; r<4; r++)
          jb.C[(size_t)(m+r)*256 + col] = f2bf((acc[mt][nt][r] + bv[nt])*cs);
      }
  } else {
    // VT[b][n][s]: 4 consecutive r = 4 consecutive s -> one 8B packed store
    #pragma unroll
    for (int mt=0; mt<4; mt++)
      #pragma unroll
      for (int nt=0; nt<4; nt++){
        int m = m0 + mt*16 + quad*4;
        int col = w*64 + nt*16 + l15;
        uint2 pk = { pk_bf16(acc[mt][nt][0]+bv[nt], acc[mt][nt][1]+bv[nt]),
                     pk_bf16(acc[mt][nt][2]+bv[nt], acc[mt][nt][3]+bv[nt]) };
        *(uint2*)&jb.C[((size_t)((m>>9)*256 + col))*512 + (m&511)] = pk;
      }
  }
}

// ---------------- MFMA GEMM with fused epilogues (single jobs) ----------------
// OUTM: 0 bf16 C[M,256] (EPI 0/1) | 3 LN(Pres+(acc+b)) -> bf16 P |
//       5 like 3 but dot outW -> fp32 logits.
template<int EPI, int OUTM>
__global__ __launch_bounds__(256,4) void k_gemm(const bf16_t* __restrict__ A,
    const bf16_t* __restrict__ Wt, const float* __restrict__ bias,
    void* __restrict__ Cv, const bf16_t* __restrict__ Pres,
    const float* __restrict__ g, const float* __restrict__ bb,
    const float* __restrict__ oW, const float* __restrict__ obp, int K)
{
  __shared__ bf16_t As[8*512];    // 8 KB
  __shared__ bf16_t Bs[32*512];   // 32 KB
  int t = threadIdx.x, w = t>>6, lane = t&63, l15 = lane&15, quad = lane>>4;
  int m0 = blockIdx.x*64;
  f32x4 z = {0.f,0.f,0.f,0.f};
  f32x4 acc[4][4] = {{z,z,z,z},{z,z,z,z},{z,z,z,z},{z,z,z,z}};

  for (int k0=0; k0<K; k0+=64){
    #pragma unroll
    for (int j=0; j<2; j++){
      int id = 2*w + j; int kc32 = id>>2, mt = id&3;
      gload16(A + (size_t)(m0 + mt*16 + l15)*K + k0 + kc32*32 + quad*8,
              &As[id*512]);
    }
    #pragma unroll
    for (int j=0; j<8; j++){
      int id = 8*w + j; int kc32 = id>>4, gnt = id&15;
      gload16(Wt + (size_t)(gnt*16 + l15)*K + k0 + kc32*32 + quad*8,
              &Bs[id*512]);
    }
    __syncthreads();
    #pragma unroll
    for (int kc=0; kc<2; kc++){
      short8 a[4], b[4];
      #pragma unroll
      for (int mt=0; mt<4; mt++) a[mt] = ld_bf8(&As[(kc*4+mt)*512 + lane*8]);
      #pragma unroll
      for (int nt=0; nt<4; nt++) b[nt] = ld_bf8(&Bs[(kc*16 + w*4 + nt)*512 + lane*8]);
      #pragma unroll
      for (int mt=0; mt<4; mt++)
        #pragma unroll
        for (int nt=0; nt<4; nt++)
          acc[mt][nt] = __builtin_amdgcn_mfma_f32_16x16x32_bf16(a[mt], b[nt], acc[mt][nt], 0,0,0);
    }
    __syncthreads();
  }

  float bv[4];
  #pragma unroll
  for (int nt=0; nt<4; nt++) bv[nt] = bias[w*64 + nt*16 + l15];

  if (OUTM==0){
    #pragma unroll
    for (int mt=0; mt<4; mt++)
      #pragma unroll
      for (int nt=0; nt<4; nt++)
        #pragma unroll
        for (int r=0; r<4; r++){
          int row = m0 + mt*16 + quad*4 + r;
          int col = w*64 + nt*16 + l15;
          float v = acc[mt][nt][r] + bv[nt];
          if (EPI==1) v = gelu_f(v);
          ((bf16_t*)Cv)[(size_t)row*256 + col] = f2bf(v);
        }
  } else {
    float* RedS = (float*)As;          // [64][4]
    float* RedQ = RedS + 256;          // [64][4]
    #pragma unroll
    for (int mt=0; mt<4; mt++)
      #pragma unroll
      for (int r=0; r<4; r++){
        int row = m0 + mt*16 + quad*4 + r;
        const bf16_t* pr = Pres + (size_t)row*256;
        float s = 0.f, q = 0.f;
        #pragma unroll
        for (int nt=0; nt<4; nt++){
          float v = acc[mt][nt][r] + bv[nt] + bf2f(pr[w*64 + nt*16 + l15]);
          s += v; q += v*v;
        }
        s += __shfl_xor(s,1); s += __shfl_xor(s,2);
        s += __shfl_xor(s,4); s += __shfl_xor(s,8);
        q += __shfl_xor(q,1); q += __shfl_xor(q,2);
        q += __shfl_xor(q,4); q += __shfl_xor(q,8);
        if (l15==0){
          int rr = mt*16 + quad*4 + r;
          RedS[rr*4 + w] = s; RedQ[rr*4 + w] = q;
        }
      }
    __syncthreads();

    float gv[4], bbv[4], wv[4];
    #pragma unroll
    for (int nt=0; nt<4; nt++){ gv[nt] = g[w*64+nt*16+l15]; bbv[nt] = bb[w*64+nt*16+l15]; }
    if (OUTM==5)
      #pragma unroll
      for (int nt=0; nt<4; nt++) wv[nt] = oW[w*64+nt*16+l15];

    float s2p[4][4];
    #pragma unroll
    for (int mt=0; mt<4; mt++)
      #pragma unroll
      for (int r=0; r<4; r++){
        int rr = mt*16 + quad*4 + r;
        int row = m0 + rr;
        float S = RedS[rr*4+0]+RedS[rr*4+1]+RedS[rr*4+2]+RedS[rr*4+3];
        float Q = RedQ[rr*4+0]+RedQ[rr*4+1]+RedQ[rr*4+2]+RedQ[rr*4+3];
        float mean = S*(1.0f/256.0f);
        float var  = Q*(1.0f/256.0f) - mean*mean;
        float rstd = rsqrtf(var + 1e-5f);
        const bf16_t* pr = Pres + (size_t)row*256;
        if (OUTM==3){
          bf16_t* po = (bf16_t*)Cv + (size_t)row*256;
          #pragma unroll
          for (int nt=0; nt<4; nt++){
            float v = acc[mt][nt][r] + bv[nt] + bf2f(pr[w*64 + nt*16 + l15]);
            po[w*64 + nt*16 + l15] = f2bf((v-mean)*rstd*gv[nt] + bbv[nt]);
          }
        } else {
          float s2 = 0.f;
          #pragma unroll
          for (int nt=0; nt<4; nt++){
            float v = acc[mt][nt][r] + bv[nt] + bf2f(pr[w*64 + nt*16 + l15]);
            s2 += ((v-mean)*rstd*gv[nt] + bbv[nt]) * wv[nt];
          }
          s2 += __shfl_xor(s2,1); s2 += __shfl_xor(s2,2);
          s2 += __shfl_xor(s2,4); s2 += __shfl_xor(s2,8);
          s2p[mt][r] = s2;
        }
      }
    if (OUTM==5){
      __syncthreads();
      #pragma unroll
      for (int mt=0; mt<4; mt++)
        #pragma unroll
        for (int r=0; r<4; r++)
          if (l15==0) RedS[(mt*16 + quad*4 + r)*4 + w] = s2p[mt][r];
      __syncthreads();
      if (w==0){
        float S = RedS[lane*4+0]+RedS[lane*4+1]+RedS[lane*4+2]+RedS[lane*4+3];
        ((float*)Cv)[m0 + lane] = S + obp[0];
      }
    }
  }
}

// ---------------- MFMA attention: r10's 1-iter-lookahead pipeline -------------
// Grid (h, b, qc). Wave = 2 q-tiles. K and V register-double-buffered: loads
// issued at iter kt2 are consumed at kt2+1. Q pre-scaled by 1/sqrt(32) in the
// Q-GEMM epilogue -> exp arg is a single add (no fma).
// S^T = mfma(aK,aQ): lane holds S[q=l15][key=ktile*16+quad*4+r].
__global__ __launch_bounds__(256) void k_attn(const bf16_t* __restrict__ Qm,
    const bf16_t* __restrict__ Km, const bf16_t* __restrict__ VT,
    const float* __restrict__ valid, bf16_t* __restrict__ AO)
{
  __shared__ bf16_t Pbuf[4][2][2][16][40];   // [wave][qtile][slot][q][key] 20 KB
  __shared__ float  Smask[512];              // 0 or -1e10
  int t = threadIdx.x, wave = t>>6, lane = t&63, l15 = lane&15, quad = lane>>4;
  int h = blockIdx.x, b = blockIdx.y, qc = blockIdx.z;
  int q0 = qc*128;

  Smask[t]     = (valid[b*Ss + t      ] != 0.f) ? 0.f : -1.0e10f;
  Smask[t+256] = (valid[b*Ss + t + 256] != 0.f) ? 0.f : -1.0e10f;
  __syncthreads();

  short8 aQ0 = ld_bf8(Qm + (size_t)(b*Ss + q0 + (wave*2  )*16 + l15)*256 + h*32 + quad*8);
  short8 aQ1 = ld_bf8(Qm + (size_t)(b*Ss + q0 + (wave*2+1)*16 + l15)*256 + h*32 + quad*8);
  const bf16_t* Kb = Km + (size_t)(b*Ss)*256 + h*32;          // + key*256
  const bf16_t* Vb = VT + ((size_t)b*256 + h*32)*512;         // + d*512 + key

  f32x4 z = {0.f,0.f,0.f,0.f};
  f32x4 O0[2] = {z,z}, O1[2] = {z,z};
  float ls0 = 0.f, ls1 = 0.f;

  // QK + exp + pack for tile kt2n into slot kt2n&1, from register K frags
  auto process = [&](int kt2n, short8 K0, short8 K1){
    int s = kt2n & 1;
    #pragma unroll
    for (int half=0; half<2; half++){
      short8 aK = half ? K1 : K0;
      int ktile = kt2n*2 + half;
      f32x4 s0 = __builtin_amdgcn_mfma_f32_16x16x32_bf16(aK, aQ0, z, 0,0,0);
      f32x4 s1 = __builtin_amdgcn_mfma_f32_16x16x32_bf16(aK, aQ1, z, 0,0,0);
      float4 mb = *(const float4*)&Smask[ktile*16 + quad*4];
      float p00 = __expf(s0[0] + mb.x);    // Q pre-scaled: add only
      float p01 = __expf(s0[1] + mb.y);
      float p02 = __expf(s0[2] + mb.z);
      float p03 = __expf(s0[3] + mb.w);
      float p10 = __expf(s1[0] + mb.x);
      float p11 = __expf(s1[1] + mb.y);
      float p12 = __expf(s1[2] + mb.z);
      float p13 = __expf(s1[3] + mb.w);
      ls0 += (p00+p01)+(p02+p03);
      ls1 += (p10+p11)+(p12+p13);
      uint2 w0 = { pk_bf16(p00,p01), pk_bf16(p02,p03) };
      uint2 w1 = { pk_bf16(p10,p11), pk_bf16(p12,p13) };
      *(uint2*)&Pbuf[wave][0][s][l15][half*16 + quad*4] = w0;
      *(uint2*)&Pbuf[wave][1][s][l15][half*16 + quad*4] = w1;
    }
  };
  auto loadK = [&](int n, short8& K0, short8& K1){
    K0 = ld_bf8(Kb + (size_t)((n*2  )*16 + l15)*256 + quad*8);
    K1 = ld_bf8(Kb + (size_t)((n*2+1)*16 + l15)*256 + quad*8);
  };
  auto loadV = [&](int n, short8& V0, short8& V1){
    V0 = ld_bf8(Vb + (size_t)(l15   )*512 + n*32 + quad*8);
    V1 = ld_bf8(Vb + (size_t)(16+l15)*512 + n*32 + quad*8);
  };

  // prologue: tile 0 processed; K(1), V(0) in flight
  short8 cK0, cK1, pK0, pK1, cV0, cV1, nK0, nK1, nV0, nV1;
  loadK(0, cK0, cK1);
  process(0, cK0, cK1);          // first-iteration bubble only
  loadK(1, pK0, pK1);
  loadV(0, cV0, cV1);

  #pragma unroll 2
  for (int kt2=0; kt2<16; kt2++){
    if (kt2+2 < 16) loadK(kt2+2, nK0, nK1);   // consumed at iter kt2+1
    if (kt2+1 < 16) loadV(kt2+1, nV0, nV1);   // consumed at iter kt2+1
    int s = kt2 & 1;
    short8 aP0 = ld_bf8(&Pbuf[wave][0][s][l15][quad*8]);
    short8 aP1 = ld_bf8(&Pbuf[wave][1][s][l15][quad*8]);
    O0[0] = __builtin_amdgcn_mfma_f32_16x16x32_bf16(aP0, cV0, O0[0], 0,0,0);
    O0[1] = __builtin_amdgcn_mfma_f32_16x16x32_bf16(aP0, cV1, O0[1], 0,0,0);
    O1[0] = __builtin_amdgcn_mfma_f32_16x16x32_bf16(aP1, cV0, O1[0], 0,0,0);
    O1[1] = __builtin_amdgcn_mfma_f32_16x16x32_bf16(aP1, cV1, O1[1], 0,0,0);
    if (kt2+1 < 16) process(kt2+1, pK0, pK1); // pK loaded a full iter ago
    pK0 = nK0; pK1 = nK1;
    cV0 = nV0; cV1 = nV1;
  }

  ls0 += __shfl_xor(ls0,16); ls0 += __shfl_xor(ls0,32);
  ls1 += __shfl_xor(ls1,16); ls1 += __shfl_xor(ls1,32);
  float linv0 = (ls0 > 0.f) ? 1.0f/ls0 : 0.f;
  float linv1 = (ls1 > 0.f) ? 1.0f/ls1 : 0.f;
  float i0[4], i1[4];
  #pragma unroll
  for (int r=0; r<4; r++){
    i0[r] = __shfl(linv0, quad*4 + r);
    i1[r] = __shfl(linv1, quad*4 + r);
  }
  size_t r0 = (size_t)(b*Ss + q0 + (wave*2  )*16);
  size_t r1 = (size_t)(b*Ss + q0 + (wave*2+1)*16);
  #pragma unroll
  for (int nt=0; nt<2; nt++)
    #pragma unroll
    for (int r=0; r<4; r++){
      AO[(r0 + quad*4 + r)*256 + h*32 + nt*16 + l15] = f2bf(O0[nt][r]*i0[r]);
      AO[(r1 + quad*4 + r)*256 + h*32 + nt*16 + l15] = f2bf(O1[nt][r]*i1[r]);
    }
}

// ---------------- final: p = exp(logits)*valid, normalize per batch -----------
__global__ __launch_bounds__(256) void k_final(const float* __restrict__ L,
    const float* __restrict__ valid, float* __restrict__ out)
{
  __shared__ float wsum[4];
  int b = blockIdx.x, t = threadIdx.x;
  float e0 = __expf(L[b*Ss + t      ]) * valid[b*Ss + t      ];
  float e1 = __expf(L[b*Ss + 256 + t]) * valid[b*Ss + 256 + t];
  float s = e0 + e1;
  #pragma unroll
  for (int o=32;o>0;o>>=1) s += __shfl_xor(s,o);
  if ((t&63)==0) wsum[t>>6] = s;
  __syncthreads();
  float tot = wsum[0]+wsum[1]+wsum[2]+wsum[3];
  out[b*Ss + t      ] = e0/tot;
  out[b*Ss + 256 + t] = e1/tot;
}

// ============================================================================
extern "C" void kernel_launch(void* const* d_in, const int* in_sizes, int n_in,
                              void* d_out, int out_size, void* d_ws, size_t ws_size,
                              hipStream_t stream)
{
  #define F(i) ((const float*)d_in[(i)])
  bool sig = (in_sizes[33] == 256);   // signature order vs dict order
  const float* d_eqW  = F(sig?35:33); const float* d_eqb  = F(sig?36:34);
  const float* d_ekW  = F(sig?37:35); const float* d_ekb  = F(sig?38:36);
  const float* d_evW  = F(sig?39:37); const float* d_evb  = F(sig?40:38);
  const float* d_eoW  = F(sig?41:39); const float* d_eob  = F(sig?42:40);
  const float* d_ln1g = F(sig?33:41); const float* d_ln1b = F(sig?34:42);

  // ---- workspace (~163 MiB) ----
  char* w = (char*)d_ws;
  bf16_t* P0 = (bf16_t*)w; w += (size_t)Mm*Hh*2;   // 32 MiB residual (enc)
  bf16_t* P1 = (bf16_t*)w; w += (size_t)Mm*Hh*2;   // 32 MiB residual (dec)
  bf16_t* H0 = (bf16_t*)w; w += (size_t)Mm*Hh*2;   // 32 MiB Q / AO / gelu
  bf16_t* H1 = (bf16_t*)w;                          // 32 MiB K / xs alias
  bf16_t* xs = (bf16_t*)w; w += (size_t)Mm*Hh*2;
  bf16_t* H2 = (bf16_t*)w;                          // 32 MiB VT / xt alias
  bf16_t* xt = (bf16_t*)w; w += (size_t)Mm*Hh*2;
  bf16_t* Wa = (bf16_t*)w; w += (size_t)(2*16384 + 16*65536)*2;  // 2.1 MiB
  float*  valid  = (float*)w; w += (size_t)Mm*4;
  float*  logits = (float*)w; w += (size_t)Mm*4;
  float* out = (float*)d_out;

  unsigned o_sem = 0, o_tem = 16384;
  unsigned o_w[16]; for (int i=0;i<16;i++) o_w[i] = 32768 + i*65536u;
  Prep18 pp;
  const float* srcs[18] = { F(5), F(7), F(9), F(11), F(13), F(15), F(19), F(21),
                            F(25), F(27), F(29), F(31), d_eqW, d_ekW, d_evW, d_eoW,
                            F(45), F(47) };
  unsigned offs[18] = { o_sem, o_tem, o_w[0],o_w[1],o_w[2],o_w[3],o_w[4],o_w[5],
                        o_w[6],o_w[7],o_w[8],o_w[9],o_w[10],o_w[11],o_w[12],o_w[13],
                        o_w[14],o_w[15] };
  for (int i=0;i<18;i++){ pp.d[i].s = srcs[i]; pp.d[i].off = offs[i]; pp.d[i].K = (i<2)?64:256; }

  dim3 blk(256);
  dim3 gLN(Mm/4);
  dim3 gG(Mm/64);
  dim3 gA(NHh, Bb, 4);
  dim3 gP(256, 18);
  const float* NF = nullptr; const bf16_t* NB = nullptr;
  const float QS = 0.17677669529663687f;   // 1/sqrt(32) folded into Q

  k_prep<<<gP, blk, 0, stream>>>(pp, Wa);
  k_ln0<<<gLN, blk, 0, stream>>>(F(0), F(1),F(2), F(3),F(4), xs, xt, valid);

  auto J = [](const bf16_t* A, const bf16_t* Wt, const float* bias, bf16_t* C,
              int outm, float cs){
    GemmJob j; j.A=A; j.Wt=Wt; j.bias=bias; j.C=C; j.outm=outm; j.cs=cs; return j;
  };

  // emb pair (independent)
  {
    GemmJobs js; js.j[0] = J(xs, Wa+o_sem, F(6), P0, 0, 1.0f);
    js.j[1] = J(xt, Wa+o_tem, F(8), P1, 0, 1.0f); js.j[2] = js.j[0];
    k_gemm3<<<dim3(Mm/64,2), blk, 0, stream>>>(js, 64);
  }

  // ---- encoder ----
  {
    GemmJobs js; js.j[0] = J(P0, Wa+o_w[0], F(10), H0, 0, QS);   // Q (pre-scaled)
    js.j[1] = J(P0, Wa+o_w[1], F(12), H1, 0, 1.0f);              // K
    js.j[2] = J(P0, Wa+o_w[2], F(14), H2, 2, 1.0f);              // V -> VT
    k_gemm3<<<dim3(Mm/64,3), blk, 0, stream>>>(js, 256);
  }
  k_attn<<<gA, blk, 0, stream>>>(H0, H1, H2, valid, H0);
  k_gemm<0,3><<<gG, blk, 0, stream>>>(H0, Wa+o_w[3], F(16), P0, P0, F(17),F(18), NF,NF, 256);
  k_gemm<1,0><<<gG, blk, 0, stream>>>(P0, Wa+o_w[4], F(20), H0, NB,NF,NF,NF,NF, 256);
  k_gemm<0,3><<<gG, blk, 0, stream>>>(H0, Wa+o_w[5], F(22), P0, P0, F(23),F(24), NF,NF, 256);

  // ---- decoder self-attention ----
  {
    GemmJobs js; js.j[0] = J(P1, Wa+o_w[6], F(26), H0, 0, QS);
    js.j[1] = J(P1, Wa+o_w[7], F(28), H1, 0, 1.0f);
    js.j[2] = J(P1, Wa+o_w[8], F(30), H2, 2, 1.0f);
    k_gemm3<<<dim3(Mm/64,3), blk, 0, stream>>>(js, 256);
  }
  k_attn<<<gA, blk, 0, stream>>>(H0, H1, H2, valid, H0);
  k_gemm<0,3><<<gG, blk, 0, stream>>>(H0, Wa+o_w[9], F(32), P1, P1, d_ln1g,d_ln1b, NF,NF, 256);

  // ---- decoder cross-attention (Q from P1; K,V from P0) ----
  {
    GemmJobs js; js.j[0] = J(P1, Wa+o_w[10], d_eqb, H0, 0, QS);
    js.j[1] = J(P0, Wa+o_w[11], d_ekb, H1, 0, 1.0f);
    js.j[2] = J(P0, Wa+o_w[12], d_evb, H2, 2, 1.0f);
    k_gemm3<<<dim3(Mm/64,3), blk, 0, stream>>>(js, 256);
  }
  k_attn<<<gA, blk, 0, stream>>>(H0, H1, H2, valid, H0);
  k_gemm<0,3><<<gG, blk, 0, stream>>>(H0, Wa+o_w[13], d_eob, P1, P1, F(43),F(44), NF,NF, 256);

  // ---- decoder FFN + fused ln3 + logits ----
  k_gemm<1,0><<<gG, blk, 0, stream>>>(P1, Wa+o_w[14], F(46), H0, NB,NF,NF,NF,NF, 256);
  k_gemm<0,5><<<gG, blk, 0, stream>>>(H0, Wa+o_w[15], F(48), logits, P1, F(49),F(50), F(51),F(52), 256);

  k_final<<<dim3(Bb), blk, 0, stream>>>(logits, valid, out);
  #undef F
}

// Round 14
// 1027.954 us; speedup vs baseline: 1.1617x; 1.0012x over previous
//
#include <hip/hip_runtime.h>
#include <hip/hip_bf16.h>

// ============================================================================
// TransformerChoiceNet forward. Round 14: fused QKV trio kernel (k_qkv) —
// full 64x256 A tile staged in LDS ONCE, three weight loops (Q*scale, K,
// V->VT) run against it: per-trio traffic 192->128 MB, barriers amortized 3x.
// Attention = r13's best (140 us). Everything else unchanged.
// B=128 S=512 D=64 H=256 NH=8 HD=32, M=B*S=65536.
// ============================================================================

#define Bb  128
#define Ss  512
#define Hh  256
#define NHh 8
#define Mm  (Bb*Ss)

typedef unsigned short bf16_t;
typedef __attribute__((ext_vector_type(8))) short short8;
typedef __attribute__((ext_vector_type(4))) float f32x4;

__device__ __forceinline__ float bf2f(bf16_t h){
  union { unsigned int u; float f; } v; v.u = ((unsigned int)h)<<16; return v.f;
}
__device__ __forceinline__ bf16_t f2bf(float f){
  union { float f; unsigned int u; } v; v.f = f;
  unsigned int r = (v.u + 0x7fffu + ((v.u>>16)&1u)) >> 16;   // RNE
  return (bf16_t)r;
}
__device__ __forceinline__ unsigned pk_bf16(float a, float b){  // packed RNE cvt
  union { __hip_bfloat162 h; unsigned u; } v;
  v.h = __float22bfloat162_rn(float2{a,b});
  return v.u;
}
__device__ __forceinline__ short8 ld_bf8(const bf16_t* p){   // 16B load
  union { uint4 u; short8 s; } v; v.u = *(const uint4*)p; return v.s;
}
__device__ __forceinline__ void gload16(const bf16_t* g, bf16_t* l){
  __builtin_amdgcn_global_load_lds(
      (const __attribute__((address_space(1))) void*)g,
      (__attribute__((address_space(3))) void*)l, 16, 0, 0);
}
__device__ __forceinline__ float gelu_f(float x){
  // NewGELU; tanh via native exp + rcp: tanh(u) = 1 - 2/(e^{2u}+1)
  float u = 0.7978845608028654f*(x + 0.044715f*x*x*x);
  float e = __expf(2.0f*u);
  float th = 1.0f - 2.0f*__builtin_amdgcn_rcpf(e + 1.0f);
  return 0.5f*x*(1.0f + th);
}

// ---------------- weight prep: fp32 W[k][n] -> bf16 Wt[n][k] ------------------
struct PrepDesc { const float* s; unsigned off; int K; };
struct Prep18  { PrepDesc d[18]; };

__global__ __launch_bounds__(256) void k_prep(Prep18 p, bf16_t* __restrict__ arena)
{
  PrepDesc dd = p.d[blockIdx.y];
  int i = blockIdx.x*256 + threadIdx.x;
  if (i < dd.K*256){
    int k = i>>8, n = i&255;
    arena[dd.off + n*dd.K + k] = f2bf(dd.s[i]);
  }
}

// ---------------- LN0 (two gains) + valid mask; bf16 out ----------------------
__global__ __launch_bounds__(256) void k_ln0(const float* __restrict__ src,
    const float* __restrict__ gs, const float* __restrict__ bs,
    const float* __restrict__ gt, const float* __restrict__ bt,
    bf16_t* __restrict__ xs, bf16_t* __restrict__ xt, float* __restrict__ valid)
{
  int row  = blockIdx.x*4 + (threadIdx.x>>6);
  int lane = threadIdx.x & 63;
  float x = src[(size_t)row*64 + lane];
  float s = x;
  #pragma unroll
  for (int o=32;o>0;o>>=1) s += __shfl_xor(s,o);
  float mean = s*(1.0f/64.0f);
  float d = x - mean;
  float ss = d*d;
  #pragma unroll
  for (int o=32;o>0;o>>=1) ss += __shfl_xor(ss,o);
  float r = rsqrtf(ss*(1.0f/64.0f) + 1e-5f);
  float xn = d*r;
  xs[(size_t)row*64+lane] = f2bf(xn*gs[lane] + bs[lane]);
  xt[(size_t)row*64+lane] = f2bf(xn*gt[lane] + bt[lane]);
  if (lane==0) valid[row] = (s != 0.0f) ? 1.0f : 0.0f;
}

// ---------------- merged independent GEMMs (emb pair, K=64) -------------------
struct GemmJob  { const bf16_t* A; const bf16_t* Wt; const float* bias; bf16_t* C;
                  int outm; float cs; };
struct GemmJobs { GemmJob j[3]; };

__global__ __launch_bounds__(256,4) void k_gemm3(GemmJobs jobs, int K)
{
  __shared__ bf16_t As[8*512];    // 8 KB
  __shared__ bf16_t Bs[32*512];   // 32 KB
  GemmJob jb = jobs.j[blockIdx.y];
  int t = threadIdx.x, w = t>>6, lane = t&63, l15 = lane&15, quad = lane>>4;
  int m0 = blockIdx.x*64;
  f32x4 z = {0.f,0.f,0.f,0.f};
  f32x4 acc[4][4] = {{z,z,z,z},{z,z,z,z},{z,z,z,z},{z,z,z,z}};

  for (int k0=0; k0<K; k0+=64){
    #pragma unroll
    for (int j=0; j<2; j++){
      int id = 2*w + j; int kc32 = id>>2, mt = id&3;
      gload16(jb.A + (size_t)(m0 + mt*16 + l15)*K + k0 + kc32*32 + quad*8,
              &As[id*512]);
    }
    #pragma unroll
    for (int j=0; j<8; j++){
      int id = 8*w + j; int kc32 = id>>4, gnt = id&15;
      gload16(jb.Wt + (size_t)(gnt*16 + l15)*K + k0 + kc32*32 + quad*8,
              &Bs[id*512]);
    }
    __syncthreads();
    #pragma unroll
    for (int kc=0; kc<2; kc++){
      short8 a[4], b[4];
      #pragma unroll
      for (int mt=0; mt<4; mt++) a[mt] = ld_bf8(&As[(kc*4+mt)*512 + lane*8]);
      #pragma unroll
      for (int nt=0; nt<4; nt++) b[nt] = ld_bf8(&Bs[(kc*16 + w*4 + nt)*512 + lane*8]);
      #pragma unroll
      for (int mt=0; mt<4; mt++)
        #pragma unroll
        for (int nt=0; nt<4; nt++)
          acc[mt][nt] = __builtin_amdgcn_mfma_f32_16x16x32_bf16(a[mt], b[nt], acc[mt][nt], 0,0,0);
    }
    __syncthreads();
  }

  float bv[4];
  #pragma unroll
  for (int nt=0; nt<4; nt++) bv[nt] = jb.bias[w*64 + nt*16 + l15];
  float cs = jb.cs;

  if (jb.outm == 0){
    #pragma unroll
    for (int mt=0; mt<4; mt++)
      #pragma unroll
      for (int nt=0; nt<4; nt++){
        int m = m0 + mt*16 + quad*4;
        int col = w*64 + nt*16 + l15;
        #pragma unroll
        for (int r=0; r<4; r++)
          jb.C[(size_t)(m+r)*256 + col] = f2bf((acc[mt][nt][r] + bv[nt])*cs);
      }
  } else {
    #pragma unroll
    for (int mt=0; mt<4; mt++)
      #pragma unroll
      for (int nt=0; nt<4; nt++){
        int m = m0 + mt*16 + quad*4;
        int col = w*64 + nt*16 + l15;
        uint2 pk = { pk_bf16(acc[mt][nt][0]+bv[nt], acc[mt][nt][1]+bv[nt]),
                     pk_bf16(acc[mt][nt][2]+bv[nt], acc[mt][nt][3]+bv[nt]) };
        *(uint2*)&jb.C[((size_t)((m>>9)*256 + col))*512 + (m&511)] = pk;
      }
  }
}

// ---------------- fused QKV trio: A staged once, 3 weight loops ---------------
// Block = 64 rows x full 256 n per output. As = full 64x256 A tile (32 KB),
// frag-block id = kc32*4+mt (kc32 0..7). Per output: 4 BK=64 W-stages into Bs.
// outm 0 = bf16 C[M,256] (cs scale), 2 = bf16 VT[b][n][s].
struct QkvJob { const bf16_t* A;
                const bf16_t* Wt0; const bf16_t* Wt1; const bf16_t* Wt2;
                const float* b0; const float* b1; const float* b2;
                bf16_t* C0; bf16_t* C1; bf16_t* C2; float qs; };

__global__ __launch_bounds__(256,2) void k_qkv(QkvJob jb)
{
  __shared__ bf16_t As[32*512];   // 32 KB: full A tile, id = kc32*4 + mt
  __shared__ bf16_t Bs[32*512];   // 32 KB: BK=64 weight tile, id = kc*16 + gnt
  int t = threadIdx.x, w = t>>6, lane = t&63, l15 = lane&15, quad = lane>>4;
  int m0 = blockIdx.x*64;
  f32x4 z = {0.f,0.f,0.f,0.f};

  #pragma unroll
  for (int j=0; j<8; j++){                    // stage FULL A once (8 per wave)
    int id = 8*w + j; int kc32 = id>>2, mt = id&3;
    gload16(jb.A + (size_t)(m0 + mt*16 + l15)*256 + kc32*32 + quad*8,
            &As[id*512]);
  }

  const bf16_t* Wts[3]  = { jb.Wt0, jb.Wt1, jb.Wt2 };
  const float*  bias[3] = { jb.b0,  jb.b1,  jb.b2  };
  bf16_t*       Cs[3]   = { jb.C0,  jb.C1,  jb.C2  };

  #pragma unroll 1
  for (int o=0; o<3; o++){
    const bf16_t* Wt = Wts[o];
    f32x4 acc[4][4] = {{z,z,z,z},{z,z,z,z},{z,z,z,z},{z,z,z,z}};
    #pragma unroll 1
    for (int ki=0; ki<4; ki++){
      #pragma unroll
      for (int j=0; j<8; j++){
        int id = 8*w + j; int kc32 = id>>4, gnt = id&15;
        gload16(Wt + (size_t)(gnt*16 + l15)*256 + ki*64 + kc32*32 + quad*8,
                &Bs[id*512]);
      }
      __syncthreads();                        // drains A stage too (first iter)
      #pragma unroll
      for (int kc=0; kc<2; kc++){
        short8 a[4], b[4];
        #pragma unroll
        for (int mt=0; mt<4; mt++)
          a[mt] = ld_bf8(&As[((ki*2+kc)*4 + mt)*512 + lane*8]);
        #pragma unroll
        for (int nt=0; nt<4; nt++)
          b[nt] = ld_bf8(&Bs[(kc*16 + w*4 + nt)*512 + lane*8]);
        #pragma unroll
        for (int mt=0; mt<4; mt++)
          #pragma unroll
          for (int nt=0; nt<4; nt++)
            acc[mt][nt] = __builtin_amdgcn_mfma_f32_16x16x32_bf16(a[mt], b[nt], acc[mt][nt], 0,0,0);
      }
      __syncthreads();                        // Bs reused next ki / next output
    }
    float bv[4];
    #pragma unroll
    for (int nt=0; nt<4; nt++) bv[nt] = bias[o][w*64 + nt*16 + l15];
    bf16_t* C = Cs[o];
    if (o < 2){                               // Q (scaled) / K: bf16 [M,256]
      float cs = (o==0) ? jb.qs : 1.0f;
      #pragma unroll
      for (int mt=0; mt<4; mt++)
        #pragma unroll
        for (int nt=0; nt<4; nt++){
          int m = m0 + mt*16 + quad*4;
          int col = w*64 + nt*16 + l15;
          #pragma unroll
          for (int r=0; r<4; r++)
            C[(size_t)(m+r)*256 + col] = f2bf((acc[mt][nt][r] + bv[nt])*cs);
        }
    } else {                                  // V -> VT[b][n][s] packed 8B
      #pragma unroll
      for (int mt=0; mt<4; mt++)
        #pragma unroll
        for (int nt=0; nt<4; nt++){
          int m = m0 + mt*16 + quad*4;
          int col = w*64 + nt*16 + l15;
          uint2 pk = { pk_bf16(acc[mt][nt][0]+bv[nt], acc[mt][nt][1]+bv[nt]),
                       pk_bf16(acc[mt][nt][2]+bv[nt], acc[mt][nt][3]+bv[nt]) };
          *(uint2*)&C[((size_t)((m>>9)*256 + col))*512 + (m&511)] = pk;
        }
    }
  }
}

// ---------------- MFMA GEMM with fused epilogues (single jobs) ----------------
// OUTM: 0 bf16 C[M,256] (EPI 0/1) | 3 LN(Pres+(acc+b)) -> bf16 P |
//       5 like 3 but dot outW -> fp32 logits.
template<int EPI, int OUTM>
__global__ __launch_bounds__(256,4) void k_gemm(const bf16_t* __restrict__ A,
    const bf16_t* __restrict__ Wt, const float* __restrict__ bias,
    void* __restrict__ Cv, const bf16_t* __restrict__ Pres,
    const float* __restrict__ g, const float* __restrict__ bb,
    const float* __restrict__ oW, const float* __restrict__ obp, int K)
{
  __shared__ bf16_t As[8*512];    // 8 KB
  __shared__ bf16_t Bs[32*512];   // 32 KB
  int t = threadIdx.x, w = t>>6, lane = t&63, l15 = lane&15, quad = lane>>4;
  int m0 = blockIdx.x*64;
  f32x4 z = {0.f,0.f,0.f,0.f};
  f32x4 acc[4][4] = {{z,z,z,z},{z,z,z,z},{z,z,z,z},{z,z,z,z}};

  for (int k0=0; k0<K; k0+=64){
    #pragma unroll
    for (int j=0; j<2; j++){
      int id = 2*w + j; int kc32 = id>>2, mt = id&3;
      gload16(A + (size_t)(m0 + mt*16 + l15)*K + k0 + kc32*32 + quad*8,
              &As[id*512]);
    }
    #pragma unroll
    for (int j=0; j<8; j++){
      int id = 8*w + j; int kc32 = id>>4, gnt = id&15;
      gload16(Wt + (size_t)(gnt*16 + l15)*K + k0 + kc32*32 + quad*8,
              &Bs[id*512]);
    }
    __syncthreads();
    #pragma unroll
    for (int kc=0; kc<2; kc++){
      short8 a[4], b[4];
      #pragma unroll
      for (int mt=0; mt<4; mt++) a[mt] = ld_bf8(&As[(kc*4+mt)*512 + lane*8]);
      #pragma unroll
      for (int nt=0; nt<4; nt++) b[nt] = ld_bf8(&Bs[(kc*16 + w*4 + nt)*512 + lane*8]);
      #pragma unroll
      for (int mt=0; mt<4; mt++)
        #pragma unroll
        for (int nt=0; nt<4; nt++)
          acc[mt][nt] = __builtin_amdgcn_mfma_f32_16x16x32_bf16(a[mt], b[nt], acc[mt][nt], 0,0,0);
    }
    __syncthreads();
  }

  float bv[4];
  #pragma unroll
  for (int nt=0; nt<4; nt++) bv[nt] = bias[w*64 + nt*16 + l15];

  if (OUTM==0){
    #pragma unroll
    for (int mt=0; mt<4; mt++)
      #pragma unroll
      for (int nt=0; nt<4; nt++)
        #pragma unroll
        for (int r=0; r<4; r++){
          int row = m0 + mt*16 + quad*4 + r;
          int col = w*64 + nt*16 + l15;
          float v = acc[mt][nt][r] + bv[nt];
          if (EPI==1) v = gelu_f(v);
          ((bf16_t*)Cv)[(size_t)row*256 + col] = f2bf(v);
        }
  } else {
    float* RedS = (float*)As;          // [64][4]
    float* RedQ = RedS + 256;          // [64][4]
    #pragma unroll
    for (int mt=0; mt<4; mt++)
      #pragma unroll
      for (int r=0; r<4; r++){
        int row = m0 + mt*16 + quad*4 + r;
        const bf16_t* pr = Pres + (size_t)row*256;
        float s = 0.f, q = 0.f;
        #pragma unroll
        for (int nt=0; nt<4; nt++){
          float v = acc[mt][nt][r] + bv[nt] + bf2f(pr[w*64 + nt*16 + l15]);
          s += v; q += v*v;
        }
        s += __shfl_xor(s,1); s += __shfl_xor(s,2);
        s += __shfl_xor(s,4); s += __shfl_xor(s,8);
        q += __shfl_xor(q,1); q += __shfl_xor(q,2);
        q += __shfl_xor(q,4); q += __shfl_xor(q,8);
        if (l15==0){
          int rr = mt*16 + quad*4 + r;
          RedS[rr*4 + w] = s; RedQ[rr*4 + w] = q;
        }
      }
    __syncthreads();

    float gv[4], bbv[4], wv[4];
    #pragma unroll
    for (int nt=0; nt<4; nt++){ gv[nt] = g[w*64+nt*16+l15]; bbv[nt] = bb[w*64+nt*16+l15]; }
    if (OUTM==5)
      #pragma unroll
      for (int nt=0; nt<4; nt++) wv[nt] = oW[w*64+nt*16+l15];

    float s2p[4][4];
    #pragma unroll
    for (int mt=0; mt<4; mt++)
      #pragma unroll
      for (int r=0; r<4; r++){
        int rr = mt*16 + quad*4 + r;
        int row = m0 + rr;
        float S = RedS[rr*4+0]+RedS[rr*4+1]+RedS[rr*4+2]+RedS[rr*4+3];
        float Q = RedQ[rr*4+0]+RedQ[rr*4+1]+RedQ[rr*4+2]+RedQ[rr*4+3];
        float mean = S*(1.0f/256.0f);
        float var  = Q*(1.0f/256.0f) - mean*mean;
        float rstd = rsqrtf(var + 1e-5f);
        const bf16_t* pr = Pres + (size_t)row*256;
        if (OUTM==3){
          bf16_t* po = (bf16_t*)Cv + (size_t)row*256;
          #pragma unroll
          for (int nt=0; nt<4; nt++){
            float v = acc[mt][nt][r] + bv[nt] + bf2f(pr[w*64 + nt*16 + l15]);
            po[w*64 + nt*16 + l15] = f2bf((v-mean)*rstd*gv[nt] + bbv[nt]);
          }
        } else {
          float s2 = 0.f;
          #pragma unroll
          for (int nt=0; nt<4; nt++){
            float v = acc[mt][nt][r] + bv[nt] + bf2f(pr[w*64 + nt*16 + l15]);
            s2 += ((v-mean)*rstd*gv[nt] + bbv[nt]) * wv[nt];
          }
          s2 += __shfl_xor(s2,1); s2 += __shfl_xor(s2,2);
          s2 += __shfl_xor(s2,4); s2 += __shfl_xor(s2,8);
          s2p[mt][r] = s2;
        }
      }
    if (OUTM==5){
      __syncthreads();
      #pragma unroll
      for (int mt=0; mt<4; mt++)
        #pragma unroll
        for (int r=0; r<4; r++)
          if (l15==0) RedS[(mt*16 + quad*4 + r)*4 + w] = s2p[mt][r];
      __syncthreads();
      if (w==0){
        float S = RedS[lane*4+0]+RedS[lane*4+1]+RedS[lane*4+2]+RedS[lane*4+3];
        ((float*)Cv)[m0 + lane] = S + obp[0];
      }
    }
  }
}

// ---------------- MFMA attention: r13's best (140 us) -------------------------
// Grid (h, b, qc). Wave = 2 q-tiles. K/V register-double-buffered, 1-iter
// lookahead. Q pre-scaled in its GEMM -> exp arg is add-only.
// S^T = mfma(aK,aQ): lane holds S[q=l15][key=ktile*16+quad*4+r].
__global__ __launch_bounds__(256) void k_attn(const bf16_t* __restrict__ Qm,
    const bf16_t* __restrict__ Km, const bf16_t* __restrict__ VT,
    const float* __restrict__ valid, bf16_t* __restrict__ AO)
{
  __shared__ bf16_t Pbuf[4][2][2][16][40];   // [wave][qtile][slot][q][key] 20 KB
  __shared__ float  Smask[512];              // 0 or -1e10
  int t = threadIdx.x, wave = t>>6, lane = t&63, l15 = lane&15, quad = lane>>4;
  int h = blockIdx.x, b = blockIdx.y, qc = blockIdx.z;
  int q0 = qc*128;

  Smask[t]     = (valid[b*Ss + t      ] != 0.f) ? 0.f : -1.0e10f;
  Smask[t+256] = (valid[b*Ss + t + 256] != 0.f) ? 0.f : -1.0e10f;
  __syncthreads();

  short8 aQ0 = ld_bf8(Qm + (size_t)(b*Ss + q0 + (wave*2  )*16 + l15)*256 + h*32 + quad*8);
  short8 aQ1 = ld_bf8(Qm + (size_t)(b*Ss + q0 + (wave*2+1)*16 + l15)*256 + h*32 + quad*8);
  const bf16_t* Kb = Km + (size_t)(b*Ss)*256 + h*32;          // + key*256
  const bf16_t* Vb = VT + ((size_t)b*256 + h*32)*512;         // + d*512 + key

  f32x4 z = {0.f,0.f,0.f,0.f};
  f32x4 O0[2] = {z,z}, O1[2] = {z,z};
  float ls0 = 0.f, ls1 = 0.f;

  auto process = [&](int kt2n, short8 K0, short8 K1){
    int s = kt2n & 1;
    #pragma unroll
    for (int half=0; half<2; half++){
      short8 aK = half ? K1 : K0;
      int ktile = kt2n*2 + half;
      f32x4 s0 = __builtin_amdgcn_mfma_f32_16x16x32_bf16(aK, aQ0, z, 0,0,0);
      f32x4 s1 = __builtin_amdgcn_mfma_f32_16x16x32_bf16(aK, aQ1, z, 0,0,0);
      float4 mb = *(const float4*)&Smask[ktile*16 + quad*4];
      float p00 = __expf(s0[0] + mb.x);    // Q pre-scaled: add only
      float p01 = __expf(s0[1] + mb.y);
      float p02 = __expf(s0[2] + mb.z);
      float p03 = __expf(s0[3] + mb.w);
      float p10 = __expf(s1[0] + mb.x);
      float p11 = __expf(s1[1] + mb.y);
      float p12 = __expf(s1[2] + mb.z);
      float p13 = __expf(s1[3] + mb.w);
      ls0 += (p00+p01)+(p02+p03);
      ls1 += (p10+p11)+(p12+p13);
      uint2 w0 = { pk_bf16(p00,p01), pk_bf16(p02,p03) };
      uint2 w1 = { pk_bf16(p10,p11), pk_bf16(p12,p13) };
      *(uint2*)&Pbuf[wave][0][s][l15][half*16 + quad*4] = w0;
      *(uint2*)&Pbuf[wave][1][s][l15][half*16 + quad*4] = w1;
    }
  };
  auto loadK = [&](int n, short8& K0, short8& K1){
    K0 = ld_bf8(Kb + (size_t)((n*2  )*16 + l15)*256 + quad*8);
    K1 = ld_bf8(Kb + (size_t)((n*2+1)*16 + l15)*256 + quad*8);
  };
  auto loadV = [&](int n, short8& V0, short8& V1){
    V0 = ld_bf8(Vb + (size_t)(l15   )*512 + n*32 + quad*8);
    V1 = ld_bf8(Vb + (size_t)(16+l15)*512 + n*32 + quad*8);
  };

  short8 cK0, cK1, pK0, pK1, cV0, cV1, nK0, nK1, nV0, nV1;
  loadK(0, cK0, cK1);
  process(0, cK0, cK1);
  loadK(1, pK0, pK1);
  loadV(0, cV0, cV1);

  #pragma unroll 2
  for (int kt2=0; kt2<16; kt2++){
    if (kt2+2 < 16) loadK(kt2+2, nK0, nK1);
    if (kt2+1 < 16) loadV(kt2+1, nV0, nV1);
    int s = kt2 & 1;
    short8 aP0 = ld_bf8(&Pbuf[wave][0][s][l15][quad*8]);
    short8 aP1 = ld_bf8(&Pbuf[wave][1][s][l15][quad*8]);
    O0[0] = __builtin_amdgcn_mfma_f32_16x16x32_bf16(aP0, cV0, O0[0], 0,0,0);
    O0[1] = __builtin_amdgcn_mfma_f32_16x16x32_bf16(aP0, cV1, O0[1], 0,0,0);
    O1[0] = __builtin_amdgcn_mfma_f32_16x16x32_bf16(aP1, cV0, O1[0], 0,0,0);
    O1[1] = __builtin_amdgcn_mfma_f32_16x16x32_bf16(aP1, cV1, O1[1], 0,0,0);
    if (kt2+1 < 16) process(kt2+1, pK0, pK1);
    pK0 = nK0; pK1 = nK1;
    cV0 = nV0; cV1 = nV1;
  }

  ls0 += __shfl_xor(ls0,16); ls0 += __shfl_xor(ls0,32);
  ls1 += __shfl_xor(ls1,16); ls1 += __shfl_xor(ls1,32);
  float linv0 = (ls0 > 0.f) ? 1.0f/ls0 : 0.f;
  float linv1 = (ls1 > 0.f) ? 1.0f/ls1 : 0.f;
  float i0[4], i1[4];
  #pragma unroll
  for (int r=0; r<4; r++){
    i0[r] = __shfl(linv0, quad*4 + r);
    i1[r] = __shfl(linv1, quad*4 + r);
  }
  size_t r0 = (size_t)(b*Ss + q0 + (wave*2  )*16);
  size_t r1 = (size_t)(b*Ss + q0 + (wave*2+1)*16);
  #pragma unroll
  for (int nt=0; nt<2; nt++)
    #pragma unroll
    for (int r=0; r<4; r++){
      AO[(r0 + quad*4 + r)*256 + h*32 + nt*16 + l15] = f2bf(O0[nt][r]*i0[r]);
      AO[(r1 + quad*4 + r)*256 + h*32 + nt*16 + l15] = f2bf(O1[nt][r]*i1[r]);
    }
}

// ---------------- final: p = exp(logits)*valid, normalize per batch -----------
__global__ __launch_bounds__(256) void k_final(const float* __restrict__ L,
    const float* __restrict__ valid, float* __restrict__ out)
{
  __shared__ float wsum[4];
  int b = blockIdx.x, t = threadIdx.x;
  float e0 = __expf(L[b*Ss + t      ]) * valid[b*Ss + t      ];
  float e1 = __expf(L[b*Ss + 256 + t]) * valid[b*Ss + 256 + t];
  float s = e0 + e1;
  #pragma unroll
  for (int o=32;o>0;o>>=1) s += __shfl_xor(s,o);
  if ((t&63)==0) wsum[t>>6] = s;
  __syncthreads();
  float tot = wsum[0]+wsum[1]+wsum[2]+wsum[3];
  out[b*Ss + t      ] = e0/tot;
  out[b*Ss + 256 + t] = e1/tot;
}

// ============================================================================
extern "C" void kernel_launch(void* const* d_in, const int* in_sizes, int n_in,
                              void* d_out, int out_size, void* d_ws, size_t ws_size,
                              hipStream_t stream)
{
  #define F(i) ((const float*)d_in[(i)])
  bool sig = (in_sizes[33] == 256);   // signature order vs dict order
  const float* d_eqW  = F(sig?35:33); const float* d_eqb  = F(sig?36:34);
  const float* d_ekW  = F(sig?37:35); const float* d_ekb  = F(sig?38:36);
  const float* d_evW  = F(sig?39:37); const float* d_evb  = F(sig?40:38);
  const float* d_eoW  = F(sig?41:39); const float* d_eob  = F(sig?42:40);
  const float* d_ln1g = F(sig?33:41); const float* d_ln1b = F(sig?34:42);

  // ---- workspace (~163 MiB) ----
  char* w = (char*)d_ws;
  bf16_t* P0 = (bf16_t*)w; w += (size_t)Mm*Hh*2;   // 32 MiB residual (enc)
  bf16_t* P1 = (bf16_t*)w; w += (size_t)Mm*Hh*2;   // 32 MiB residual (dec)
  bf16_t* H0 = (bf16_t*)w; w += (size_t)Mm*Hh*2;   // 32 MiB Q / AO / gelu
  bf16_t* H1 = (bf16_t*)w;                          // 32 MiB K / xs alias
  bf16_t* xs = (bf16_t*)w; w += (size_t)Mm*Hh*2;
  bf16_t* H2 = (bf16_t*)w;                          // 32 MiB VT / xt alias
  bf16_t* xt = (bf16_t*)w; w += (size_t)Mm*Hh*2;
  bf16_t* Wa = (bf16_t*)w; w += (size_t)(2*16384 + 16*65536)*2;  // 2.1 MiB
  float*  valid  = (float*)w; w += (size_t)Mm*4;
  float*  logits = (float*)w; w += (size_t)Mm*4;
  float* out = (float*)d_out;

  unsigned o_sem = 0, o_tem = 16384;
  unsigned o_w[16]; for (int i=0;i<16;i++) o_w[i] = 32768 + i*65536u;
  Prep18 pp;
  const float* srcs[18] = { F(5), F(7), F(9), F(11), F(13), F(15), F(19), F(21),
                            F(25), F(27), F(29), F(31), d_eqW, d_ekW, d_evW, d_eoW,
                            F(45), F(47) };
  unsigned offs[18] = { o_sem, o_tem, o_w[0],o_w[1],o_w[2],o_w[3],o_w[4],o_w[5],
                        o_w[6],o_w[7],o_w[8],o_w[9],o_w[10],o_w[11],o_w[12],o_w[13],
                        o_w[14],o_w[15] };
  for (int i=0;i<18;i++){ pp.d[i].s = srcs[i]; pp.d[i].off = offs[i]; pp.d[i].K = (i<2)?64:256; }

  dim3 blk(256);
  dim3 gLN(Mm/4);
  dim3 gG(Mm/64);
  dim3 gA(NHh, Bb, 4);
  dim3 gP(256, 18);
  const float* NF = nullptr; const bf16_t* NB = nullptr;
  const float QS = 0.17677669529663687f;   // 1/sqrt(32) folded into Q

  k_prep<<<gP, blk, 0, stream>>>(pp, Wa);
  k_ln0<<<gLN, blk, 0, stream>>>(F(0), F(1),F(2), F(3),F(4), xs, xt, valid);

  // emb pair (independent, K=64)
  {
    GemmJobs js;
    js.j[0] = { xs, Wa+o_sem, F(6), P0, 0, 1.0f };
    js.j[1] = { xt, Wa+o_tem, F(8), P1, 0, 1.0f };
    js.j[2] = js.j[0];
    k_gemm3<<<dim3(Mm/64,2), blk, 0, stream>>>(js, 64);
  }

  auto QJ = [&](const bf16_t* A, int wq, int wk, int wv,
                const float* bq, const float* bk, const float* bv2,
                const bf16_t* Ak){
    QkvJob j; j.A = A;
    j.Wt0 = Wa+o_w[wq]; j.Wt1 = Wa+o_w[wk]; j.Wt2 = Wa+o_w[wv];
    j.b0 = bq; j.b1 = bk; j.b2 = bv2;
    j.C0 = H0; j.C1 = H1; j.C2 = H2; j.qs = QS;
    (void)Ak; return j;
  };

  // ---- encoder ----
  {
    QkvJob j = QJ(P0, 0,1,2, F(10),F(12),F(14), P0);
    k_qkv<<<gG, blk, 0, stream>>>(j);
  }
  k_attn<<<gA, blk, 0, stream>>>(H0, H1, H2, valid, H0);
  k_gemm<0,3><<<gG, blk, 0, stream>>>(H0, Wa+o_w[3], F(16), P0, P0, F(17),F(18), NF,NF, 256);
  k_gemm<1,0><<<gG, blk, 0, stream>>>(P0, Wa+o_w[4], F(20), H0, NB,NF,NF,NF,NF, 256);
  k_gemm<0,3><<<gG, blk, 0, stream>>>(H0, Wa+o_w[5], F(22), P0, P0, F(23),F(24), NF,NF, 256);

  // ---- decoder self-attention ----
  {
    QkvJob j = QJ(P1, 6,7,8, F(26),F(28),F(30), P1);
    k_qkv<<<gG, blk, 0, stream>>>(j);
  }
  k_attn<<<gA, blk, 0, stream>>>(H0, H1, H2, valid, H0);
  k_gemm<0,3><<<gG, blk, 0, stream>>>(H0, Wa+o_w[9], F(32), P1, P1, d_ln1g,d_ln1b, NF,NF, 256);

  // ---- decoder cross-attention: Q from P1, K/V from P0 -> K/V via trio on P0
  // is not shareable with Q's A; run Q as single k_gemm and K/V as 2-job trio.
  {
    k_gemm<0,0><<<gG, blk, 0, stream>>>(P1, Wa+o_w[10], d_eqb, H0, NB,NF,NF,NF,NF, 256);
    // K and V share A=P0: use k_qkv with Q-slot pointed at K (qs=1) would
    // triple-run; instead use k_gemm3 2-job for K,V (A re-read 2x, still -32MB
    // vs 3 singles) -- keep k_gemm3 here.
    GemmJobs js;
    js.j[0] = { P0, Wa+o_w[11], d_ekb, H1, 0, 1.0f };
    js.j[1] = { P0, Wa+o_w[12], d_evb, H2, 2, 1.0f };
    js.j[2] = js.j[0];
    k_gemm3<<<dim3(Mm/64,2), blk, 0, stream>>>(js, 256);
  }
  k_attn<<<gA, blk, 0, stream>>>(H0, H1, H2, valid, H0);
  k_gemm<0,3><<<gG, blk, 0, stream>>>(H0, Wa+o_w[13], d_eob, P1, P1, F(43),F(44), NF,NF, 256);

  // ---- decoder FFN + fused ln3 + logits ----
  k_gemm<1,0><<<gG, blk, 0, stream>>>(P1, Wa+o_w[14], F(46), H0, NB,NF,NF,NF,NF, 256);
  k_gemm<0,5><<<gG, blk, 0, stream>>>(H0, Wa+o_w[15], F(48), logits, P1, F(49),F(50), F(51),F(52), 256);

  k_final<<<dim3(Bb), blk, 0, stream>>>(logits, valid, out);
  #undef F
}